// Round 10
// baseline (1908.865 us; speedup 1.0000x reference)
//
#include <hip/hip_runtime.h>
#include <math.h>
#include <stdint.h>

#define NN 100000
#define NE 1600000
#define GIN 128
#define GH 64
#define GOUT 10
#define NG 512
#define TPB 256
#define SCB 1024
#define NB ((NN + SCB - 1) / SCB)   // 98 scan blocks
#define MMBLK 1024                  // blocks for MFMA matmuls
#define ECH 1024                    // edges per scatter chunk
#define ENCH ((NE + ECH - 1) / ECH) // 1563
#define NCH (NN / 32)               // 3125 node chunks (32 nodes each)

typedef __attribute__((ext_vector_type(8))) short bf16x8;
typedef __attribute__((ext_vector_type(4))) float f32x4;

// ---- bf16 helpers (RNE pack) ----
__device__ __forceinline__ float bflo(uint32_t u) { return __uint_as_float(u << 16); }
__device__ __forceinline__ float bfhi(uint32_t u) { return __uint_as_float(u & 0xFFFF0000u); }
__device__ __forceinline__ uint32_t f2bf(float f) {
  uint32_t b = __float_as_uint(f);
  return (b + 0x7FFFu + ((b >> 16) & 1u)) >> 16;
}
__device__ __forceinline__ uint32_t pack2(float lo, float hi) { return f2bf(lo) | (f2bf(hi) << 16); }
__device__ __forceinline__ short bfs(float f) { return (short)f2bf(f); }

// hardware XCD id (gfx940+: HW_REG_XCC_ID = id 20; read 4 bits). If this id is
// wrong on some part, values are garbage — the work-steal loops below still
// drain every queue, so correctness never depends on it (only locality).
__device__ __forceinline__ int xcc_id() {
  return (int)(__builtin_amdgcn_s_getreg((3u << 11) | 20u) & 7u);
}

__global__ void k_zero_i(int* __restrict__ p, int n) {
  int i = blockIdx.x * TPB + threadIdx.x;
  if (i < n) p[i] = 0;
}

__global__ void k_hist(const int* __restrict__ col, int* __restrict__ deg) {
  int e = blockIdx.x * TPB + threadIdx.x;
  if (e < NE) atomicAdd(&deg[col[e]], 1);
}

__global__ void k_dinv(const int* __restrict__ deg, float* __restrict__ dinv) {
  int i = blockIdx.x * TPB + threadIdx.x;
  if (i < NN) dinv[i] = rsqrtf((float)deg[i] + 1.0f);  // +1 self-loop
}

__global__ void k_gstart(const int* __restrict__ batch, int* __restrict__ gstart) {
  int g = blockIdx.x * TPB + threadIdx.x;
  if (g > NG) return;
  int lo = 0, hi = NN;
  while (lo < hi) { int mid = (lo + hi) >> 1; if (batch[mid] < g) lo = mid + 1; else hi = mid; }
  gstart[g] = lo;
}

__global__ void k_scan1(const int* __restrict__ deg, int* __restrict__ pref,
                        int* __restrict__ bsum) {
  __shared__ int wsum[8];
  int t = threadIdx.x;
  int base = blockIdx.x * SCB;
  int v[4]; int s = 0;
#pragma unroll
  for (int j = 0; j < 4; ++j) {
    int idx = base + t * 4 + j;
    v[j] = (idx < NN) ? deg[idx] : 0;
    s += v[j];
  }
  int lane = t & 63, wid = t >> 6;
  int sc = s;
#pragma unroll
  for (int off = 1; off < 64; off <<= 1) {
    int u = __shfl_up(sc, off);
    if (lane >= off) sc += u;
  }
  if (lane == 63) wsum[wid] = sc;
  __syncthreads();
  if (t == 0) {
    int a = 0;
    for (int w = 0; w < 4; ++w) { int x = wsum[w]; wsum[w] = a; a += x; }
  }
  __syncthreads();
  int excl = sc - s + wsum[wid];
#pragma unroll
  for (int j = 0; j < 4; ++j) {
    int idx = base + t * 4 + j;
    if (idx < NN) pref[idx] = excl;
    excl += v[j];
  }
  if (t == TPB - 1) bsum[blockIdx.x] = excl;  // block total
}

__global__ void k_scan2(int* __restrict__ bsum) {
  __shared__ int l[NB];
  int t = threadIdx.x;
  if (t < NB) l[t] = bsum[t];
  __syncthreads();
  if (t == 0) {
    int a = 0;
    for (int i = 0; i < NB; ++i) { int x = l[i]; l[i] = a; a += x; }
  }
  __syncthreads();
  if (t < NB) bsum[t] = l[t];
}

__global__ void k_scan3(const int* __restrict__ pref, const int* __restrict__ bsum,
                        int* __restrict__ rowptr, int* __restrict__ cursor) {
  int i = blockIdx.x * TPB + threadIdx.x;
  if (i < NN) {
    int v = pref[i] + bsum[i / SCB];
    rowptr[i] = v;
    cursor[i] = v;
  }
  if (i == NN) rowptr[NN] = NE;
}

// XCC-pinned scatter: wave drains edge-chunk queue of part = its real XCD, so
// that part's cursor+esrc slice stays in ONE L2. Steal loop guarantees drain.
__global__ void k_scatter_q(const int* __restrict__ row, const int* __restrict__ col,
                            int* __restrict__ cursor, int* __restrict__ esrc,
                            int* __restrict__ eq) {
  int xcc = xcc_id();
  int lane = threadIdx.x & 63;
  for (int t = 0; t < 8; ++t) {
    int part = (xcc + t) & 7;
    int lo = part * (NN / 8), hi = lo + (NN / 8);
    while (true) {
      int ch;
      if (lane == 0) ch = atomicAdd(&eq[part], 1);
      ch = __shfl(ch, 0);
      if (ch >= ENCH) break;
      int base = ch * ECH;
#pragma unroll
      for (int i = 0; i < ECH / 64; ++i) {
        int e = base + i * 64 + lane;
        if (e < NE) {
          int c = col[e];
          if (c >= lo && c < hi) {
            int p = atomicAdd(&cursor[c], 1);
            esrc[p] = row[e];
          }
        }
      }
    }
  }
}

// ---- MFMA matmul, layer 1: X f32 [NN,128] @ W1 -> blocked bf16 Y[4][NN][16], *dinv ----
__global__ __launch_bounds__(TPB, 1)
void k_mm1(const float* __restrict__ X, const float* __restrict__ W,
           const float* __restrict__ dinv, ushort* __restrict__ Y) {
  int lane = threadIdx.x & 63;
  int wv = blockIdx.x * (TPB / 64) + (threadIdx.x >> 6);
  const int nwv = MMBLK * (TPB / 64);
  int kb = (lane >> 4) * 8;
  int fcol = lane & 15;
  bf16x8 bfr[4][4];
#pragma unroll
  for (int kt = 0; kt < 4; ++kt)
#pragma unroll
    for (int ct = 0; ct < 4; ++ct)
#pragma unroll
      for (int j = 0; j < 8; ++j)
        bfr[kt][ct][j] = bfs(W[(size_t)(kt * 32 + kb + j) * GH + ct * 16 + fcol]);
  const int NT = NN / 16;
  for (int t = wv; t < NT; t += nwv) {
    int n0 = t * 16;
    const float* xr = X + (size_t)(n0 + fcol) * GIN;
    f32x4 acc[4] = {{0,0,0,0},{0,0,0,0},{0,0,0,0},{0,0,0,0}};
#pragma unroll
    for (int kt = 0; kt < 4; ++kt) {
      float4 p = *(const float4*)(xr + kt * 32 + kb);
      float4 q = *(const float4*)(xr + kt * 32 + kb + 4);
      bf16x8 a;
      a[0] = bfs(p.x); a[1] = bfs(p.y); a[2] = bfs(p.z); a[3] = bfs(p.w);
      a[4] = bfs(q.x); a[5] = bfs(q.y); a[6] = bfs(q.z); a[7] = bfs(q.w);
#pragma unroll
      for (int ct = 0; ct < 4; ++ct)
        acc[ct] = __builtin_amdgcn_mfma_f32_16x16x32_bf16(a, bfr[kt][ct], acc[ct], 0, 0, 0);
    }
    int rbase = (lane >> 4) * 4;
#pragma unroll
    for (int reg = 0; reg < 4; ++reg) {
      int n = n0 + rbase + reg;
      float d = dinv[n];
#pragma unroll
      for (int ct = 0; ct < 4; ++ct)
        Y[((size_t)ct * NN + n) * 16 + fcol] = (ushort)f2bf(acc[ct][reg] * d);
    }
  }
}

// ---- MFMA matmul, layers 2/3: blocked bf16 X[4][NN][16] @ W -> blocked bf16 Y, *dinv ----
__global__ __launch_bounds__(TPB, 1)
void k_mmh(const ushort* __restrict__ X, const float* __restrict__ W,
           const float* __restrict__ dinv, ushort* __restrict__ Y) {
  int lane = threadIdx.x & 63;
  int wv = blockIdx.x * (TPB / 64) + (threadIdx.x >> 6);
  const int nwv = MMBLK * (TPB / 64);
  int kb = (lane >> 4) * 8;
  int fcol = lane & 15;
  bf16x8 bfr[2][4];
#pragma unroll
  for (int kt = 0; kt < 2; ++kt)
#pragma unroll
    for (int ct = 0; ct < 4; ++ct)
#pragma unroll
      for (int j = 0; j < 8; ++j)
        bfr[kt][ct][j] = bfs(W[(size_t)(kt * 32 + kb + j) * GH + ct * 16 + fcol]);
  int abk = (lane >> 5);            // block contribution from kb
  int aoff = ((lane >> 4) & 1) * 8; // 0/8 within block
  const int NT = NN / 16;
  for (int t = wv; t < NT; t += nwv) {
    int n0 = t * 16;
    f32x4 acc[4] = {{0,0,0,0},{0,0,0,0},{0,0,0,0},{0,0,0,0}};
#pragma unroll
    for (int kt = 0; kt < 2; ++kt) {
      bf16x8 a = *(const bf16x8*)(X + (((size_t)(kt * 2 + abk) * NN + n0 + fcol) * 16 + aoff));
#pragma unroll
      for (int ct = 0; ct < 4; ++ct)
        acc[ct] = __builtin_amdgcn_mfma_f32_16x16x32_bf16(a, bfr[kt][ct], acc[ct], 0, 0, 0);
    }
    int rbase = (lane >> 4) * 4;
#pragma unroll
    for (int reg = 0; reg < 4; ++reg) {
      int n = n0 + rbase + reg;
      float d = dinv[n];
#pragma unroll
      for (int ct = 0; ct < 4; ++ct)
        Y[((size_t)ct * NN + n) * 16 + fcol] = (ushort)f2bf(acc[ct][reg] * d);
    }
  }
}

// XCC-pinned feature-blocked aggregation: wave drains node-chunk queue of
// ct = (its XCD)>>1, gathering only from that ct's 3.2 MB sub-table (fits L2).
// 2 lanes per node (h = lane&1 -> 8 feats), 32 nodes/chunk, register acc.
template<bool RELU, bool SCALE_SRC, bool BIAS>
__global__ void k_aggq(const int* __restrict__ rowptr, const int* __restrict__ esrc,
                       const float* __restrict__ dinv, const ushort* __restrict__ hp,
                       const float* __restrict__ bias, ushort* __restrict__ out,
                       int* __restrict__ wq) {
  int xcc = xcc_id();
  int lane = threadIdx.x & 63;
  int h = lane & 1;
  for (int t = 0; t < 4; ++t) {
    int ct = ((xcc >> 1) + t) & 3;
    const ushort* tbl = hp + (size_t)ct * NN * 16;
    ushort* ot = out + (size_t)ct * NN * 16;
    while (true) {
      int ch;
      if (lane == 0) ch = atomicAdd(&wq[ct], 1);
      ch = __shfl(ch, 0);
      if (ch >= NCH) break;
      int n = ch * 32 + (lane >> 1);
      int s0 = rowptr[n], s1 = rowptr[n + 1];
      float acc[8] = {0.f, 0.f, 0.f, 0.f, 0.f, 0.f, 0.f, 0.f};
      int e = s0;
      for (; e + 1 < s1; e += 2) {
        int r0 = esrc[e], r1 = esrc[e + 1];
        uint4 v0 = *(const uint4*)(tbl + (size_t)r0 * 16 + h * 8);
        uint4 v1 = *(const uint4*)(tbl + (size_t)r1 * 16 + h * 8);
        float d0 = 1.f, d1 = 1.f;
        if (SCALE_SRC) { d0 = dinv[r0]; d1 = dinv[r1]; }
        acc[0] += bflo(v0.x) * d0; acc[1] += bfhi(v0.x) * d0;
        acc[2] += bflo(v0.y) * d0; acc[3] += bfhi(v0.y) * d0;
        acc[4] += bflo(v0.z) * d0; acc[5] += bfhi(v0.z) * d0;
        acc[6] += bflo(v0.w) * d0; acc[7] += bfhi(v0.w) * d0;
        acc[0] += bflo(v1.x) * d1; acc[1] += bfhi(v1.x) * d1;
        acc[2] += bflo(v1.y) * d1; acc[3] += bfhi(v1.y) * d1;
        acc[4] += bflo(v1.z) * d1; acc[5] += bfhi(v1.z) * d1;
        acc[6] += bflo(v1.w) * d1; acc[7] += bfhi(v1.w) * d1;
      }
      if (e < s1) {
        int r = esrc[e];
        uint4 v = *(const uint4*)(tbl + (size_t)r * 16 + h * 8);
        float d = SCALE_SRC ? dinv[r] : 1.f;
        acc[0] += bflo(v.x) * d; acc[1] += bfhi(v.x) * d;
        acc[2] += bflo(v.y) * d; acc[3] += bfhi(v.y) * d;
        acc[4] += bflo(v.z) * d; acc[5] += bfhi(v.z) * d;
        acc[6] += bflo(v.w) * d; acc[7] += bfhi(v.w) * d;
      }
      float dn = dinv[n];
      uint4 sv = *(const uint4*)(tbl + (size_t)n * 16 + h * 8);
      float sc = SCALE_SRC ? dn : 1.f;
      float r8[8];
      r8[0] = (acc[0] + bflo(sv.x) * sc) * dn; r8[1] = (acc[1] + bfhi(sv.x) * sc) * dn;
      r8[2] = (acc[2] + bflo(sv.y) * sc) * dn; r8[3] = (acc[3] + bfhi(sv.y) * sc) * dn;
      r8[4] = (acc[4] + bflo(sv.z) * sc) * dn; r8[5] = (acc[5] + bfhi(sv.z) * sc) * dn;
      r8[6] = (acc[6] + bflo(sv.w) * sc) * dn; r8[7] = (acc[7] + bfhi(sv.w) * sc) * dn;
      if (BIAS) {
        const float* bp = bias + ct * 16 + h * 8;
        float4 bA = *(const float4*)bp, bB = *(const float4*)(bp + 4);
        r8[0] += bA.x; r8[1] += bA.y; r8[2] += bA.z; r8[3] += bA.w;
        r8[4] += bB.x; r8[5] += bB.y; r8[6] += bB.z; r8[7] += bB.w;
      }
      if (RELU) {
#pragma unroll
        for (int i = 0; i < 8; ++i) r8[i] = fmaxf(r8[i], 0.f);
      }
      uint4 o;
      o.x = pack2(r8[0], r8[1]); o.y = pack2(r8[2], r8[3]);
      o.z = pack2(r8[4], r8[5]); o.w = pack2(r8[6], r8[7]);
      *(uint4*)(ot + (size_t)n * 16 + h * 8) = o;
    }
  }
}

// per-graph segmented sum over sorted batch; input blocked [4][NN][16]
__global__ void k_pool(const ushort* __restrict__ agg4, const int* __restrict__ gstart,
                       float* __restrict__ P) {
  __shared__ float part[4][GH];
  int g = blockIdx.x;
  int f = threadIdx.x & 63, r = threadIdx.x >> 6;
  int blk = f >> 4, off = f & 15;
  const ushort* src = agg4 + (size_t)blk * NN * 16 + off;
  int a = gstart[g], b = gstart[g + 1];
  float acc = 0.f;
  for (int n = a + r; n < b; n += 4)
    acc += __uint_as_float(((uint32_t)src[(size_t)n * 16]) << 16);
  part[r][f] = acc;
  __syncthreads();
  if (r == 0) P[(size_t)g * GH + f] = part[0][f] + part[1][f] + part[2][f] + part[3][f];
}

__global__ void k_head(const float* __restrict__ P, const int* __restrict__ gstart,
                       const float* __restrict__ W4, const float* __restrict__ b4,
                       float* __restrict__ out) {
  int g = blockIdx.x;
  int lane = threadIdx.x;  // 64
  float c = fmaxf((float)(gstart[g + 1] - gstart[g]), 1.0f);
  float p = P[(size_t)g * GH + lane] / c;
  float t[GOUT];
#pragma unroll
  for (int j = 0; j < GOUT; ++j) {
    float r = p * W4[lane * GOUT + j];
#pragma unroll
    for (int off = 1; off < 64; off <<= 1) r += __shfl_xor(r, off);
    t[j] = r + b4[j];
  }
  if (lane == 0) {
    float mx = -1e30f;
#pragma unroll
    for (int j = 0; j < GOUT; ++j) mx = fmaxf(mx, t[j]);
    float sum = 0.f;
#pragma unroll
    for (int j = 0; j < GOUT; ++j) sum += expf(t[j] - mx);
    float lse = mx + logf(sum);
#pragma unroll
    for (int j = 0; j < GOUT; ++j) out[(size_t)g * GOUT + j] = t[j] - lse;
  }
}

static inline int cdiv(long a, long b) { return (int)((a + b - 1) / b); }

extern "C" void kernel_launch(void* const* d_in, const int* in_sizes, int n_in,
                              void* d_out, int out_size, void* d_ws, size_t ws_size,
                              hipStream_t stream) {
  const float* x  = (const float*)d_in[0];
  const int*   ei = (const int*)d_in[1];
  const int*   bt = (const int*)d_in[2];
  const float* W1 = (const float*)d_in[3];
  const float* b1 = (const float*)d_in[4];
  const float* W2 = (const float*)d_in[5];
  const float* b2 = (const float*)d_in[6];
  const float* W3 = (const float*)d_in[7];
  const float* b3 = (const float*)d_in[8];
  const float* W4 = (const float*)d_in[9];
  const float* b4 = (const float*)d_in[10];
  float* out = (float*)d_out;

  ushort* HP   = (ushort*)d_ws;                       // NN*64 bf16 (blocked [4][NN][16])
  ushort* ACT  = HP + (size_t)NN * GH;                // NN*64 bf16 (blocked)
  float* dinv  = (float*)(ACT + (size_t)NN * GH);     // NN
  float* P     = dinv + NN;                           // NG*64
  int* gstart  = (int*)(P + (size_t)NG * GH);         // NG+1
  int* deg     = gstart + NG + 3;                     // NN
  int* pref    = deg + NN;                            // NN
  int* rowptr  = pref + NN;                           // NN+1
  int* cursor  = rowptr + NN + 1;                     // NN
  int* bsum    = cursor + NN;                         // NB
  int* esrc    = bsum + ((NB + 3) & ~3);              // NE
  int* wq      = esrc + NE;                           // 16 (4 layers x 4 cts)
  int* eq      = wq + 16;                             // 8 (scatter parts)

  const int* row = ei;        // edge_index[0] = source
  const int* col = ei + NE;   // edge_index[1] = target (aggregate here)

  // --- zero queues + deg ---
  k_zero_i<<<cdiv(NN, TPB), TPB, 0, stream>>>(deg, NN);
  k_zero_i<<<1, TPB, 0, stream>>>(wq, 24);  // wq[16] + eq[8] contiguous
  k_hist<<<cdiv(NE, TPB), TPB, 0, stream>>>(col, deg);
  k_dinv<<<cdiv(NN, TPB), TPB, 0, stream>>>(deg, dinv);
  k_gstart<<<cdiv(NG + 1, TPB), TPB, 0, stream>>>(bt, gstart);
  k_scan1<<<NB, TPB, 0, stream>>>(deg, pref, bsum);
  k_scan2<<<1, TPB, 0, stream>>>(bsum);
  k_scan3<<<cdiv(NN + 1, TPB), TPB, 0, stream>>>(pref, bsum, rowptr, cursor);
  k_scatter_q<<<512, TPB, 0, stream>>>(row, col, cursor, esrc, eq);

  // --- layer 1 ---
  k_mm1<<<MMBLK, TPB, 0, stream>>>(x, W1, dinv, HP);
  k_aggq<true, false, true><<<1024, TPB, 0, stream>>>(rowptr, esrc, dinv, HP, b1, ACT, wq);
  // --- layer 2 ---
  k_mmh<<<MMBLK, TPB, 0, stream>>>(ACT, W2, dinv, HP);
  k_aggq<true, false, true><<<1024, TPB, 0, stream>>>(rowptr, esrc, dinv, HP, b2, ACT, wq + 4);
  // --- layer 3 ---
  k_mmh<<<MMBLK, TPB, 0, stream>>>(ACT, W3, dinv, HP);
  k_aggq<true, false, true><<<1024, TPB, 0, stream>>>(rowptr, esrc, dinv, HP, b3, ACT, wq + 8);
  // --- layer 4 (algebraic swap): AGG4 = Â·H3 into HP, no bias/relu ---
  k_aggq<false, true, false><<<1024, TPB, 0, stream>>>(rowptr, esrc, dinv, ACT, nullptr, HP, wq + 12);

  // --- pool + head ---
  k_pool<<<NG, TPB, 0, stream>>>(HP, gstart, P);
  k_head<<<NG, 64, 0, stream>>>(P, gstart, W4, b4, out);
}

// Round 11
// 360.229 us; speedup vs baseline: 5.2990x; 5.2990x over previous
//
#include <hip/hip_runtime.h>
#include <math.h>
#include <stdint.h>

#define NN 100000
#define NE 1600000
#define GIN 128
#define GH 64
#define GOUT 10
#define NG 512
#define TPB 256
#define SCB 1024
#define NB ((NN + SCB - 1) / SCB)   // 98 scan blocks
#define MMBLK 1024                  // blocks for MFMA matmuls (4096 waves)
#define SPB 128                     // scatter blocks per dst-part (grid = 8*SPB)

typedef __attribute__((ext_vector_type(8))) short bf16x8;
typedef __attribute__((ext_vector_type(4))) float f32x4;

// ---- bf16 helpers (RNE pack) ----
__device__ __forceinline__ float bflo(uint32_t u) { return __uint_as_float(u << 16); }
__device__ __forceinline__ float bfhi(uint32_t u) { return __uint_as_float(u & 0xFFFF0000u); }
__device__ __forceinline__ uint32_t f2bf(float f) {
  uint32_t b = __float_as_uint(f);
  return (b + 0x7FFFu + ((b >> 16) & 1u)) >> 16;
}
__device__ __forceinline__ uint32_t pack2(float lo, float hi) { return f2bf(lo) | (f2bf(hi) << 16); }
__device__ __forceinline__ short bfs(float f) { return (short)f2bf(f); }

__global__ void k_zero_i(int* __restrict__ p, int n) {
  int i = blockIdx.x * TPB + threadIdx.x;
  if (i < n) p[i] = 0;
}

// histogram of in-degrees; the returned old value IS this edge's rank among
// edges sharing its destination — persist it so the scatter needs no atomics.
__global__ void k_hist(const int* __restrict__ col, int* __restrict__ deg,
                       ushort* __restrict__ rank) {
  int e = blockIdx.x * TPB + threadIdx.x;
  if (e < NE) {
    int r = atomicAdd(&deg[col[e]], 1);
    rank[e] = (ushort)r;
  }
}

__global__ void k_dinv(const int* __restrict__ deg, float* __restrict__ dinv) {
  int i = blockIdx.x * TPB + threadIdx.x;
  if (i < NN) dinv[i] = rsqrtf((float)deg[i] + 1.0f);  // +1 self-loop
}

// gstart[g] = first node index with batch >= g (batch sorted); gstart[NG] = NN
__global__ void k_gstart(const int* __restrict__ batch, int* __restrict__ gstart) {
  int g = blockIdx.x * TPB + threadIdx.x;
  if (g > NG) return;
  int lo = 0, hi = NN;
  while (lo < hi) { int mid = (lo + hi) >> 1; if (batch[mid] < g) lo = mid + 1; else hi = mid; }
  gstart[g] = lo;
}

__global__ void k_scan1(const int* __restrict__ deg, int* __restrict__ pref,
                        int* __restrict__ bsum) {
  __shared__ int wsum[8];
  int t = threadIdx.x;
  int base = blockIdx.x * SCB;
  int v[4]; int s = 0;
#pragma unroll
  for (int j = 0; j < 4; ++j) {
    int idx = base + t * 4 + j;
    v[j] = (idx < NN) ? deg[idx] : 0;
    s += v[j];
  }
  int lane = t & 63, wid = t >> 6;
  int sc = s;
#pragma unroll
  for (int off = 1; off < 64; off <<= 1) {
    int u = __shfl_up(sc, off);
    if (lane >= off) sc += u;
  }
  if (lane == 63) wsum[wid] = sc;
  __syncthreads();
  if (t == 0) {
    int a = 0;
    for (int w = 0; w < 4; ++w) { int x = wsum[w]; wsum[w] = a; a += x; }
  }
  __syncthreads();
  int excl = sc - s + wsum[wid];
#pragma unroll
  for (int j = 0; j < 4; ++j) {
    int idx = base + t * 4 + j;
    if (idx < NN) pref[idx] = excl;
    excl += v[j];
  }
  if (t == TPB - 1) bsum[blockIdx.x] = excl;  // block total
}

__global__ void k_scan2(int* __restrict__ bsum) {
  __shared__ int l[NB];
  int t = threadIdx.x;
  if (t < NB) l[t] = bsum[t];
  __syncthreads();
  if (t == 0) {
    int a = 0;
    for (int i = 0; i < NB; ++i) { int x = l[i]; l[i] = a; a += x; }
  }
  __syncthreads();
  if (t < NB) bsum[t] = l[t];
}

__global__ void k_scan3(const int* __restrict__ pref, const int* __restrict__ bsum,
                        int* __restrict__ rowptr) {
  int i = blockIdx.x * TPB + threadIdx.x;
  if (i < NN) rowptr[i] = pref[i] + bsum[i / SCB];
  if (i == NN) rowptr[NN] = NE;
}

// Atomic-free scatter: each edge's esrc slot = rowptr[dst] + rank (from hist).
// 8-way dst-partition kept for write locality (blocks of a part write one
// contiguous 1/8 esrc slice).
__global__ void k_scatter_r(const int* __restrict__ row, const int* __restrict__ col,
                            const ushort* __restrict__ rank, const int* __restrict__ rowptr,
                            int* __restrict__ esrc) {
  int part = blockIdx.x & 7;
  int lo = part * (NN / 8), hi = lo + (NN / 8);  // NN/8 = 12500 exact
  for (int e = (blockIdx.x >> 3) * TPB + threadIdx.x; e < NE; e += SPB * TPB) {
    int c = col[e];
    if (c >= lo && c < hi) esrc[rowptr[c] + (int)rank[e]] = row[e];
  }
}

// ---- MFMA matmul, layer 1: X f32 [NN,128] @ W1[128,64] -> bf16 Y [NN,64], *dinv ----
__global__ __launch_bounds__(TPB, 1)
void k_mm1(const float* __restrict__ X, const float* __restrict__ W,
           const float* __restrict__ dinv, ushort* __restrict__ Y) {
  int lane = threadIdx.x & 63;
  int wv = blockIdx.x * (TPB / 64) + (threadIdx.x >> 6);
  const int nwv = MMBLK * (TPB / 64);
  int kb = (lane >> 4) * 8;   // k-base within a 32-k tile
  int fcol = lane & 15;       // B col / C col / A row index
  bf16x8 bfr[4][4];
#pragma unroll
  for (int kt = 0; kt < 4; ++kt)
#pragma unroll
    for (int ct = 0; ct < 4; ++ct)
#pragma unroll
      for (int j = 0; j < 8; ++j)
        bfr[kt][ct][j] = bfs(W[(size_t)(kt * 32 + kb + j) * GH + ct * 16 + fcol]);
  const int NT = NN / 16;  // 6250
  for (int t = wv; t < NT; t += nwv) {
    int n0 = t * 16;
    const float* xr = X + (size_t)(n0 + fcol) * GIN;
    f32x4 acc[4] = {{0,0,0,0},{0,0,0,0},{0,0,0,0},{0,0,0,0}};
#pragma unroll
    for (int kt = 0; kt < 4; ++kt) {
      float4 p = *(const float4*)(xr + kt * 32 + kb);
      float4 q = *(const float4*)(xr + kt * 32 + kb + 4);
      bf16x8 a;
      a[0] = bfs(p.x); a[1] = bfs(p.y); a[2] = bfs(p.z); a[3] = bfs(p.w);
      a[4] = bfs(q.x); a[5] = bfs(q.y); a[6] = bfs(q.z); a[7] = bfs(q.w);
#pragma unroll
      for (int ct = 0; ct < 4; ++ct)
        acc[ct] = __builtin_amdgcn_mfma_f32_16x16x32_bf16(a, bfr[kt][ct], acc[ct], 0, 0, 0);
    }
    int rbase = (lane >> 4) * 4;
#pragma unroll
    for (int reg = 0; reg < 4; ++reg) {
      int n = n0 + rbase + reg;
      float d = dinv[n];
#pragma unroll
      for (int ct = 0; ct < 4; ++ct)
        Y[(size_t)n * GH + ct * 16 + fcol] = (ushort)f2bf(acc[ct][reg] * d);
    }
  }
}

// ---- MFMA matmul, layers 2/3: X bf16 [NN,64] @ W[64,64] -> bf16 Y, *dinv ----
__global__ __launch_bounds__(TPB, 1)
void k_mmh(const ushort* __restrict__ X, const float* __restrict__ W,
           const float* __restrict__ dinv, ushort* __restrict__ Y) {
  int lane = threadIdx.x & 63;
  int wv = blockIdx.x * (TPB / 64) + (threadIdx.x >> 6);
  const int nwv = MMBLK * (TPB / 64);
  int kb = (lane >> 4) * 8;
  int fcol = lane & 15;
  bf16x8 bfr[2][4];
#pragma unroll
  for (int kt = 0; kt < 2; ++kt)
#pragma unroll
    for (int ct = 0; ct < 4; ++ct)
#pragma unroll
      for (int j = 0; j < 8; ++j)
        bfr[kt][ct][j] = bfs(W[(size_t)(kt * 32 + kb + j) * GH + ct * 16 + fcol]);
  const int NT = NN / 16;
  for (int t = wv; t < NT; t += nwv) {
    int n0 = t * 16;
    const ushort* xr = X + (size_t)(n0 + fcol) * GH;
    f32x4 acc[4] = {{0,0,0,0},{0,0,0,0},{0,0,0,0},{0,0,0,0}};
#pragma unroll
    for (int kt = 0; kt < 2; ++kt) {
      bf16x8 a = *(const bf16x8*)(xr + kt * 32 + kb);
#pragma unroll
      for (int ct = 0; ct < 4; ++ct)
        acc[ct] = __builtin_amdgcn_mfma_f32_16x16x32_bf16(a, bfr[kt][ct], acc[ct], 0, 0, 0);
    }
    int rbase = (lane >> 4) * 4;
#pragma unroll
    for (int reg = 0; reg < 4; ++reg) {
      int n = n0 + rbase + reg;
      float d = dinv[n];
#pragma unroll
      for (int ct = 0; ct < 4; ++ct)
        Y[(size_t)n * GH + ct * 16 + fcol] = (ushort)f2bf(acc[ct][reg] * d);
    }
  }
}

// One wave per node; 8 groups of 8 lanes; group q handles edges s0+q, s0+q+8, ...
// Each lane loads uint4 = 8 bf16 feats (full 128 B row per 8-lane group = one
// cache line, zero overfetch). acc f32; cross-group shfl reduction.
template<bool RELU, bool SCALE_SRC, bool BIAS>
__global__ void k_agg(const int* __restrict__ rowptr, const int* __restrict__ esrc,
                      const float* __restrict__ dinv, const uint4* __restrict__ hp,
                      const float* __restrict__ bias, uint4* __restrict__ out) {
  int n = blockIdx.x * (TPB / 64) + (threadIdx.x >> 6);
  if (n >= NN) return;
  int lane = threadIdx.x & 63;
  int qid = lane >> 3, fq = lane & 7;
  int s0 = rowptr[n], s1 = rowptr[n + 1];
  float acc[8] = {0.f, 0.f, 0.f, 0.f, 0.f, 0.f, 0.f, 0.f};
  int e = s0 + qid;
  for (; e + 8 < s1; e += 16) {
    int r0 = esrc[e], r1 = esrc[e + 8];
    uint4 v0 = hp[(size_t)r0 * 8 + fq];
    uint4 v1 = hp[(size_t)r1 * 8 + fq];
    float d0 = 1.f, d1 = 1.f;
    if (SCALE_SRC) { d0 = dinv[r0]; d1 = dinv[r1]; }
    acc[0] += bflo(v0.x) * d0; acc[1] += bfhi(v0.x) * d0;
    acc[2] += bflo(v0.y) * d0; acc[3] += bfhi(v0.y) * d0;
    acc[4] += bflo(v0.z) * d0; acc[5] += bfhi(v0.z) * d0;
    acc[6] += bflo(v0.w) * d0; acc[7] += bfhi(v0.w) * d0;
    acc[0] += bflo(v1.x) * d1; acc[1] += bfhi(v1.x) * d1;
    acc[2] += bflo(v1.y) * d1; acc[3] += bfhi(v1.y) * d1;
    acc[4] += bflo(v1.z) * d1; acc[5] += bfhi(v1.z) * d1;
    acc[6] += bflo(v1.w) * d1; acc[7] += bfhi(v1.w) * d1;
  }
  if (e < s1) {
    int r = esrc[e];
    uint4 v = hp[(size_t)r * 8 + fq];
    float d = SCALE_SRC ? dinv[r] : 1.f;
    acc[0] += bflo(v.x) * d; acc[1] += bfhi(v.x) * d;
    acc[2] += bflo(v.y) * d; acc[3] += bfhi(v.y) * d;
    acc[4] += bflo(v.z) * d; acc[5] += bfhi(v.z) * d;
    acc[6] += bflo(v.w) * d; acc[7] += bfhi(v.w) * d;
  }
#pragma unroll
  for (int off = 8; off < 64; off <<= 1) {
#pragma unroll
    for (int i = 0; i < 8; ++i) acc[i] += __shfl_xor(acc[i], off);
  }
  if (qid == 0) {
    float dn = dinv[n];
    uint4 sv = hp[(size_t)n * 8 + fq];
    float sc = SCALE_SRC ? dn : 1.f;
    float r[8];
    r[0] = (acc[0] + bflo(sv.x) * sc) * dn; r[1] = (acc[1] + bfhi(sv.x) * sc) * dn;
    r[2] = (acc[2] + bflo(sv.y) * sc) * dn; r[3] = (acc[3] + bfhi(sv.y) * sc) * dn;
    r[4] = (acc[4] + bflo(sv.z) * sc) * dn; r[5] = (acc[5] + bfhi(sv.z) * sc) * dn;
    r[6] = (acc[6] + bflo(sv.w) * sc) * dn; r[7] = (acc[7] + bfhi(sv.w) * sc) * dn;
    if (BIAS) {
      const float4* b4p = (const float4*)bias;
      float4 bA = b4p[fq * 2], bB = b4p[fq * 2 + 1];
      r[0] += bA.x; r[1] += bA.y; r[2] += bA.z; r[3] += bA.w;
      r[4] += bB.x; r[5] += bB.y; r[6] += bB.z; r[7] += bB.w;
    }
    if (RELU) {
#pragma unroll
      for (int i = 0; i < 8; ++i) r[i] = fmaxf(r[i], 0.f);
    }
    uint4 o;
    o.x = pack2(r[0], r[1]); o.y = pack2(r[2], r[3]);
    o.z = pack2(r[4], r[5]); o.w = pack2(r[6], r[7]);
    out[(size_t)n * 8 + fq] = o;
  }
}

// per-graph segmented sum over sorted batch; input flat [NN][64]
__global__ void k_pool(const ushort* __restrict__ agg4, const int* __restrict__ gstart,
                       float* __restrict__ P) {
  __shared__ float part[4][GH];
  int g = blockIdx.x;
  int f = threadIdx.x & 63, r = threadIdx.x >> 6;
  int a = gstart[g], b = gstart[g + 1];
  float acc = 0.f;
  for (int n = a + r; n < b; n += 4)
    acc += __uint_as_float(((uint32_t)agg4[(size_t)n * GH + f]) << 16);
  part[r][f] = acc;
  __syncthreads();
  if (r == 0) P[(size_t)g * GH + f] = part[0][f] + part[1][f] + part[2][f] + part[3][f];
}

__global__ void k_head(const float* __restrict__ P, const int* __restrict__ gstart,
                       const float* __restrict__ W4, const float* __restrict__ b4,
                       float* __restrict__ out) {
  int g = blockIdx.x;
  int lane = threadIdx.x;  // 64
  float c = fmaxf((float)(gstart[g + 1] - gstart[g]), 1.0f);
  float p = P[(size_t)g * GH + lane] / c;
  float t[GOUT];
#pragma unroll
  for (int j = 0; j < GOUT; ++j) {
    float r = p * W4[lane * GOUT + j];
#pragma unroll
    for (int off = 1; off < 64; off <<= 1) r += __shfl_xor(r, off);
    t[j] = r + b4[j];
  }
  if (lane == 0) {
    float mx = -1e30f;
#pragma unroll
    for (int j = 0; j < GOUT; ++j) mx = fmaxf(mx, t[j]);
    float sum = 0.f;
#pragma unroll
    for (int j = 0; j < GOUT; ++j) sum += expf(t[j] - mx);
    float lse = mx + logf(sum);
#pragma unroll
    for (int j = 0; j < GOUT; ++j) out[(size_t)g * GOUT + j] = t[j] - lse;
  }
}

static inline int cdiv(long a, long b) { return (int)((a + b - 1) / b); }

extern "C" void kernel_launch(void* const* d_in, const int* in_sizes, int n_in,
                              void* d_out, int out_size, void* d_ws, size_t ws_size,
                              hipStream_t stream) {
  const float* x  = (const float*)d_in[0];
  const int*   ei = (const int*)d_in[1];
  const int*   bt = (const int*)d_in[2];
  const float* W1 = (const float*)d_in[3];
  const float* b1 = (const float*)d_in[4];
  const float* W2 = (const float*)d_in[5];
  const float* b2 = (const float*)d_in[6];
  const float* W3 = (const float*)d_in[7];
  const float* b3 = (const float*)d_in[8];
  const float* W4 = (const float*)d_in[9];
  const float* b4 = (const float*)d_in[10];
  float* out = (float*)d_out;

  ushort* HP   = (ushort*)d_ws;                       // NN*64 bf16
  ushort* ACT  = HP + (size_t)NN * GH;                // NN*64 bf16
  ushort* rank = ACT + (size_t)NN * GH;               // NE ushort
  float* dinv  = (float*)(rank + NE);                 // NN
  float* P     = dinv + NN;                           // NG*64
  int* gstart  = (int*)(P + (size_t)NG * GH);         // NG+1
  int* deg     = gstart + NG + 3;                     // NN
  int* pref    = deg + NN;                            // NN
  int* rowptr  = pref + NN;                           // NN+1
  int* bsum    = rowptr + NN + 1;                     // NB
  int* esrc    = bsum + ((NB + 3) & ~3);              // NE

  const int* row = ei;        // edge_index[0] = source
  const int* col = ei + NE;   // edge_index[1] = target (aggregate here)

  // --- CSR build (rank-based, atomic-free scatter) + dinv + graph starts ---
  k_zero_i<<<cdiv(NN, TPB), TPB, 0, stream>>>(deg, NN);
  k_hist<<<cdiv(NE, TPB), TPB, 0, stream>>>(col, deg, rank);
  k_dinv<<<cdiv(NN, TPB), TPB, 0, stream>>>(deg, dinv);
  k_gstart<<<cdiv(NG + 1, TPB), TPB, 0, stream>>>(bt, gstart);
  k_scan1<<<NB, TPB, 0, stream>>>(deg, pref, bsum);
  k_scan2<<<1, TPB, 0, stream>>>(bsum);
  k_scan3<<<cdiv(NN + 1, TPB), TPB, 0, stream>>>(pref, bsum, rowptr);
  k_scatter_r<<<8 * SPB, TPB, 0, stream>>>(row, col, rank, rowptr, esrc);

  const int gridN = cdiv(NN, TPB / 64);

  // --- layer 1 ---
  k_mm1<<<MMBLK, TPB, 0, stream>>>(x, W1, dinv, HP);
  k_agg<true, false, true><<<gridN, TPB, 0, stream>>>(rowptr, esrc, dinv, (const uint4*)HP, b1, (uint4*)ACT);
  // --- layer 2 ---
  k_mmh<<<MMBLK, TPB, 0, stream>>>(ACT, W2, dinv, HP);
  k_agg<true, false, true><<<gridN, TPB, 0, stream>>>(rowptr, esrc, dinv, (const uint4*)HP, b2, (uint4*)ACT);
  // --- layer 3 ---
  k_mmh<<<MMBLK, TPB, 0, stream>>>(ACT, W3, dinv, HP);
  k_agg<true, false, true><<<gridN, TPB, 0, stream>>>(rowptr, esrc, dinv, (const uint4*)HP, b3, (uint4*)ACT);
  // --- layer 4 (algebraic swap): AGG4 = Â·H3 into HP, no bias/relu ---
  k_agg<false, true, false><<<gridN, TPB, 0, stream>>>(rowptr, esrc, dinv, (const uint4*)ACT, nullptr, (uint4*)HP);

  // --- pool + head ---
  k_pool<<<NG, TPB, 0, stream>>>(HP, gstart, P);
  k_head<<<NG, 64, 0, stream>>>(P, gstart, W4, b4, out);
}

// Round 12
// 326.789 us; speedup vs baseline: 5.8413x; 1.1023x over previous
//
#include <hip/hip_runtime.h>
#include <math.h>
#include <stdint.h>

#define NN 100000
#define NE 1600000
#define GIN 128
#define GH 64
#define GOUT 10
#define NG 512
#define TPB 256
#define MMBLK 1024                  // blocks for MFMA matmuls (4096 waves)
#define NBKT ((NN + 127) >> 7)      // 782 buckets of 128 nodes
#define BA 256                      // blocks for bucket passes
#define CHA ((NE + BA - 1) / BA)    // 6250 edges per block

typedef __attribute__((ext_vector_type(8))) short bf16x8;
typedef __attribute__((ext_vector_type(4))) float f32x4;

// ---- bf16 helpers (RNE pack) ----
__device__ __forceinline__ float bflo(uint32_t u) { return __uint_as_float(u << 16); }
__device__ __forceinline__ float bfhi(uint32_t u) { return __uint_as_float(u & 0xFFFF0000u); }
__device__ __forceinline__ uint32_t f2bf(float f) {
  uint32_t b = __float_as_uint(f);
  return (b + 0x7FFFu + ((b >> 16) & 1u)) >> 16;
}
__device__ __forceinline__ uint32_t pack2(float lo, float hi) { return f2bf(lo) | (f2bf(hi) << 16); }
__device__ __forceinline__ short bfs(float f) { return (short)f2bf(f); }

__global__ void k_zero_i(int* __restrict__ p, int n) {
  int i = blockIdx.x * TPB + threadIdx.x;
  if (i < n) p[i] = 0;
}

// gstart[g] = first node index with batch >= g (batch sorted); gstart[NG] = NN
__global__ void k_gstart(const int* __restrict__ batch, int* __restrict__ gstart) {
  int g = blockIdx.x * TPB + threadIdx.x;
  if (g > NG) return;
  int lo = 0, hi = NN;
  while (lo < hi) { int mid = (lo + hi) >> 1; if (batch[mid] < g) lo = mid + 1; else hi = mid; }
  gstart[g] = lo;
}

// ---- bucketed CSR build (no fine-grained global atomics) ----
// Pass A1: per-block LDS histogram over buckets; coarse merge to btot.
__global__ void k_bcount(const int* __restrict__ col, int* __restrict__ btot) {
  __shared__ int cnt[NBKT];
  for (int k = threadIdx.x; k < NBKT; k += TPB) cnt[k] = 0;
  __syncthreads();
  int e0 = blockIdx.x * CHA, e1 = min(e0 + CHA, NE);
  for (int e = e0 + threadIdx.x; e < e1; e += TPB)
    atomicAdd(&cnt[col[e] >> 7], 1);
  __syncthreads();
  for (int k = threadIdx.x; k < NBKT; k += TPB)
    if (cnt[k]) atomicAdd(&btot[k], cnt[k]);
}

// Pass A-scan: exclusive scan of 782 bucket totals (tiny, serial).
__global__ void k_bscan(const int* __restrict__ btot, int* __restrict__ ebase) {
  if (threadIdx.x == 0) {
    int a = 0;
    for (int k = 0; k < NBKT; ++k) { ebase[k] = a; a += btot[k]; }
    ebase[NBKT] = a;  // == NE
  }
}

// Pass A2: re-count in LDS, claim per-(block,bucket) chunk, write packed edges
// (row | colLow<<17) into contiguous bucket regions.
__global__ void k_bscatter(const int* __restrict__ row, const int* __restrict__ col,
                           const int* __restrict__ ebase, int* __restrict__ bcur,
                           uint32_t* __restrict__ packed) {
  __shared__ int cnt[NBKT];
  __shared__ int bas[NBKT];
  for (int k = threadIdx.x; k < NBKT; k += TPB) cnt[k] = 0;
  __syncthreads();
  int e0 = blockIdx.x * CHA, e1 = min(e0 + CHA, NE);
  for (int e = e0 + threadIdx.x; e < e1; e += TPB)
    atomicAdd(&cnt[col[e] >> 7], 1);
  __syncthreads();
  for (int k = threadIdx.x; k < NBKT; k += TPB)
    bas[k] = cnt[k] ? ebase[k] + atomicAdd(&bcur[k], cnt[k]) : 0;
  __syncthreads();
  for (int k = threadIdx.x; k < NBKT; k += TPB) cnt[k] = 0;  // reuse as cursor
  __syncthreads();
  for (int e = e0 + threadIdx.x; e < e1; e += TPB) {
    int c = col[e];
    int k = c >> 7;
    int off = atomicAdd(&cnt[k], 1);
    packed[bas[k] + off] = (uint32_t)row[e] | ((uint32_t)(c & 127) << 17);
  }
}

// Pass B: one block per bucket — 128-bin LDS hist -> rowptr/dinv + esrc scatter
// (LDS atomics only; writes land in this bucket's contiguous ~8KB esrc window).
__global__ void k_bbuild(const uint32_t* __restrict__ packed, const int* __restrict__ ebase,
                         int* __restrict__ rowptr, float* __restrict__ dinv,
                         int* __restrict__ esrc) {
  __shared__ int hist[128], hptr[128], off[128];
  int bkt = blockIdx.x;
  int s0 = ebase[bkt], s1 = ebase[bkt + 1];
  int n0 = bkt << 7;
  int nloc = min(128, NN - n0);
  for (int k = threadIdx.x; k < 128; k += TPB) { hist[k] = 0; off[k] = 0; }
  __syncthreads();
  for (int i = s0 + threadIdx.x; i < s1; i += TPB)
    atomicAdd(&hist[packed[i] >> 17], 1);
  __syncthreads();
  if (threadIdx.x == 0) {
    int a = 0;
    for (int k = 0; k < 128; ++k) { hptr[k] = a; a += hist[k]; }
  }
  __syncthreads();
  if (threadIdx.x < nloc) {
    int k = threadIdx.x;
    rowptr[n0 + k] = s0 + hptr[k];
    dinv[n0 + k] = rsqrtf((float)hist[k] + 1.0f);  // +1 self-loop
  }
  if (bkt == NBKT - 1 && threadIdx.x == 0) rowptr[NN] = NE;
  for (int i = s0 + threadIdx.x; i < s1; i += TPB) {
    uint32_t u = packed[i];
    int k = (int)(u >> 17);
    int r = atomicAdd(&off[k], 1);
    esrc[s0 + hptr[k] + r] = (int)(u & 0x1FFFFu);
  }
}

// ---- MFMA matmul, layer 1: X f32 [NN,128] @ W1[128,64] -> bf16 Y [NN,64], *dinv ----
__global__ __launch_bounds__(TPB, 1)
void k_mm1(const float* __restrict__ X, const float* __restrict__ W,
           const float* __restrict__ dinv, ushort* __restrict__ Y) {
  int lane = threadIdx.x & 63;
  int wv = blockIdx.x * (TPB / 64) + (threadIdx.x >> 6);
  const int nwv = MMBLK * (TPB / 64);
  int kb = (lane >> 4) * 8;   // k-base within a 32-k tile
  int fcol = lane & 15;       // B col / C col / A row index
  bf16x8 bfr[4][4];
#pragma unroll
  for (int kt = 0; kt < 4; ++kt)
#pragma unroll
    for (int ct = 0; ct < 4; ++ct)
#pragma unroll
      for (int j = 0; j < 8; ++j)
        bfr[kt][ct][j] = bfs(W[(size_t)(kt * 32 + kb + j) * GH + ct * 16 + fcol]);
  const int NT = NN / 16;  // 6250
  for (int t = wv; t < NT; t += nwv) {
    int n0 = t * 16;
    const float* xr = X + (size_t)(n0 + fcol) * GIN;
    f32x4 acc[4] = {{0,0,0,0},{0,0,0,0},{0,0,0,0},{0,0,0,0}};
#pragma unroll
    for (int kt = 0; kt < 4; ++kt) {
      float4 p = *(const float4*)(xr + kt * 32 + kb);
      float4 q = *(const float4*)(xr + kt * 32 + kb + 4);
      bf16x8 a;
      a[0] = bfs(p.x); a[1] = bfs(p.y); a[2] = bfs(p.z); a[3] = bfs(p.w);
      a[4] = bfs(q.x); a[5] = bfs(q.y); a[6] = bfs(q.z); a[7] = bfs(q.w);
#pragma unroll
      for (int ct = 0; ct < 4; ++ct)
        acc[ct] = __builtin_amdgcn_mfma_f32_16x16x32_bf16(a, bfr[kt][ct], acc[ct], 0, 0, 0);
    }
    int rbase = (lane >> 4) * 4;
#pragma unroll
    for (int reg = 0; reg < 4; ++reg) {
      int n = n0 + rbase + reg;
      float d = dinv[n];
#pragma unroll
      for (int ct = 0; ct < 4; ++ct)
        Y[(size_t)n * GH + ct * 16 + fcol] = (ushort)f2bf(acc[ct][reg] * d);
    }
  }
}

// ---- MFMA matmul, layers 2/3: X bf16 [NN,64] @ W[64,64] -> bf16 Y, *dinv ----
__global__ __launch_bounds__(TPB, 1)
void k_mmh(const ushort* __restrict__ X, const float* __restrict__ W,
           const float* __restrict__ dinv, ushort* __restrict__ Y) {
  int lane = threadIdx.x & 63;
  int wv = blockIdx.x * (TPB / 64) + (threadIdx.x >> 6);
  const int nwv = MMBLK * (TPB / 64);
  int kb = (lane >> 4) * 8;
  int fcol = lane & 15;
  bf16x8 bfr[2][4];
#pragma unroll
  for (int kt = 0; kt < 2; ++kt)
#pragma unroll
    for (int ct = 0; ct < 4; ++ct)
#pragma unroll
      for (int j = 0; j < 8; ++j)
        bfr[kt][ct][j] = bfs(W[(size_t)(kt * 32 + kb + j) * GH + ct * 16 + fcol]);
  const int NT = NN / 16;
  for (int t = wv; t < NT; t += nwv) {
    int n0 = t * 16;
    const ushort* xr = X + (size_t)(n0 + fcol) * GH;
    f32x4 acc[4] = {{0,0,0,0},{0,0,0,0},{0,0,0,0},{0,0,0,0}};
#pragma unroll
    for (int kt = 0; kt < 2; ++kt) {
      bf16x8 a = *(const bf16x8*)(xr + kt * 32 + kb);
#pragma unroll
      for (int ct = 0; ct < 4; ++ct)
        acc[ct] = __builtin_amdgcn_mfma_f32_16x16x32_bf16(a, bfr[kt][ct], acc[ct], 0, 0, 0);
    }
    int rbase = (lane >> 4) * 4;
#pragma unroll
    for (int reg = 0; reg < 4; ++reg) {
      int n = n0 + rbase + reg;
      float d = dinv[n];
#pragma unroll
      for (int ct = 0; ct < 4; ++ct)
        Y[(size_t)n * GH + ct * 16 + fcol] = (ushort)f2bf(acc[ct][reg] * d);
    }
  }
}

// One wave per node; 8 groups of 8 lanes; group q handles edges s0+q, s0+q+8, ...
// Each lane loads uint4 = 8 bf16 feats (full 128 B row per 8-lane group = one
// cache line, zero overfetch). acc f32; cross-group shfl reduction.
template<bool RELU, bool SCALE_SRC, bool BIAS>
__global__ void k_agg(const int* __restrict__ rowptr, const int* __restrict__ esrc,
                      const float* __restrict__ dinv, const uint4* __restrict__ hp,
                      const float* __restrict__ bias, uint4* __restrict__ out) {
  int n = blockIdx.x * (TPB / 64) + (threadIdx.x >> 6);
  if (n >= NN) return;
  int lane = threadIdx.x & 63;
  int qid = lane >> 3, fq = lane & 7;
  int s0 = rowptr[n], s1 = rowptr[n + 1];
  float acc[8] = {0.f, 0.f, 0.f, 0.f, 0.f, 0.f, 0.f, 0.f};
  int e = s0 + qid;
  for (; e + 8 < s1; e += 16) {
    int r0 = esrc[e], r1 = esrc[e + 8];
    uint4 v0 = hp[(size_t)r0 * 8 + fq];
    uint4 v1 = hp[(size_t)r1 * 8 + fq];
    float d0 = 1.f, d1 = 1.f;
    if (SCALE_SRC) { d0 = dinv[r0]; d1 = dinv[r1]; }
    acc[0] += bflo(v0.x) * d0; acc[1] += bfhi(v0.x) * d0;
    acc[2] += bflo(v0.y) * d0; acc[3] += bfhi(v0.y) * d0;
    acc[4] += bflo(v0.z) * d0; acc[5] += bfhi(v0.z) * d0;
    acc[6] += bflo(v0.w) * d0; acc[7] += bfhi(v0.w) * d0;
    acc[0] += bflo(v1.x) * d1; acc[1] += bfhi(v1.x) * d1;
    acc[2] += bflo(v1.y) * d1; acc[3] += bfhi(v1.y) * d1;
    acc[4] += bflo(v1.z) * d1; acc[5] += bfhi(v1.z) * d1;
    acc[6] += bflo(v1.w) * d1; acc[7] += bfhi(v1.w) * d1;
  }
  if (e < s1) {
    int r = esrc[e];
    uint4 v = hp[(size_t)r * 8 + fq];
    float d = SCALE_SRC ? dinv[r] : 1.f;
    acc[0] += bflo(v.x) * d; acc[1] += bfhi(v.x) * d;
    acc[2] += bflo(v.y) * d; acc[3] += bfhi(v.y) * d;
    acc[4] += bflo(v.z) * d; acc[5] += bfhi(v.z) * d;
    acc[6] += bflo(v.w) * d; acc[7] += bfhi(v.w) * d;
  }
#pragma unroll
  for (int off = 8; off < 64; off <<= 1) {
#pragma unroll
    for (int i = 0; i < 8; ++i) acc[i] += __shfl_xor(acc[i], off);
  }
  if (qid == 0) {
    float dn = dinv[n];
    uint4 sv = hp[(size_t)n * 8 + fq];
    float sc = SCALE_SRC ? dn : 1.f;
    float r[8];
    r[0] = (acc[0] + bflo(sv.x) * sc) * dn; r[1] = (acc[1] + bfhi(sv.x) * sc) * dn;
    r[2] = (acc[2] + bflo(sv.y) * sc) * dn; r[3] = (acc[3] + bfhi(sv.y) * sc) * dn;
    r[4] = (acc[4] + bflo(sv.z) * sc) * dn; r[5] = (acc[5] + bfhi(sv.z) * sc) * dn;
    r[6] = (acc[6] + bflo(sv.w) * sc) * dn; r[7] = (acc[7] + bfhi(sv.w) * sc) * dn;
    if (BIAS) {
      const float4* b4p = (const float4*)bias;
      float4 bA = b4p[fq * 2], bB = b4p[fq * 2 + 1];
      r[0] += bA.x; r[1] += bA.y; r[2] += bA.z; r[3] += bA.w;
      r[4] += bB.x; r[5] += bB.y; r[6] += bB.z; r[7] += bB.w;
    }
    if (RELU) {
#pragma unroll
      for (int i = 0; i < 8; ++i) r[i] = fmaxf(r[i], 0.f);
    }
    uint4 o;
    o.x = pack2(r[0], r[1]); o.y = pack2(r[2], r[3]);
    o.z = pack2(r[4], r[5]); o.w = pack2(r[6], r[7]);
    out[(size_t)n * 8 + fq] = o;
  }
}

// per-graph segmented sum over sorted batch; input flat [NN][64]
__global__ void k_pool(const ushort* __restrict__ agg4, const int* __restrict__ gstart,
                       float* __restrict__ P) {
  __shared__ float part[4][GH];
  int g = blockIdx.x;
  int f = threadIdx.x & 63, r = threadIdx.x >> 6;
  int a = gstart[g], b = gstart[g + 1];
  float acc = 0.f;
  for (int n = a + r; n < b; n += 4)
    acc += __uint_as_float(((uint32_t)agg4[(size_t)n * GH + f]) << 16);
  part[r][f] = acc;
  __syncthreads();
  if (r == 0) P[(size_t)g * GH + f] = part[0][f] + part[1][f] + part[2][f] + part[3][f];
}

__global__ void k_head(const float* __restrict__ P, const int* __restrict__ gstart,
                       const float* __restrict__ W4, const float* __restrict__ b4,
                       float* __restrict__ out) {
  int g = blockIdx.x;
  int lane = threadIdx.x;  // 64
  float c = fmaxf((float)(gstart[g + 1] - gstart[g]), 1.0f);
  float p = P[(size_t)g * GH + lane] / c;
  float t[GOUT];
#pragma unroll
  for (int j = 0; j < GOUT; ++j) {
    float r = p * W4[lane * GOUT + j];
#pragma unroll
    for (int off = 1; off < 64; off <<= 1) r += __shfl_xor(r, off);
    t[j] = r + b4[j];
  }
  if (lane == 0) {
    float mx = -1e30f;
#pragma unroll
    for (int j = 0; j < GOUT; ++j) mx = fmaxf(mx, t[j]);
    float sum = 0.f;
#pragma unroll
    for (int j = 0; j < GOUT; ++j) sum += expf(t[j] - mx);
    float lse = mx + logf(sum);
#pragma unroll
    for (int j = 0; j < GOUT; ++j) out[(size_t)g * GOUT + j] = t[j] - lse;
  }
}

static inline int cdiv(long a, long b) { return (int)((a + b - 1) / b); }

extern "C" void kernel_launch(void* const* d_in, const int* in_sizes, int n_in,
                              void* d_out, int out_size, void* d_ws, size_t ws_size,
                              hipStream_t stream) {
  const float* x  = (const float*)d_in[0];
  const int*   ei = (const int*)d_in[1];
  const int*   bt = (const int*)d_in[2];
  const float* W1 = (const float*)d_in[3];
  const float* b1 = (const float*)d_in[4];
  const float* W2 = (const float*)d_in[5];
  const float* b2 = (const float*)d_in[6];
  const float* W3 = (const float*)d_in[7];
  const float* b3 = (const float*)d_in[8];
  const float* W4 = (const float*)d_in[9];
  const float* b4 = (const float*)d_in[10];
  float* out = (float*)d_out;

  ushort* HP      = (ushort*)d_ws;                    // NN*64 bf16
  ushort* ACT     = HP + (size_t)NN * GH;             // NN*64 bf16
  float* dinv     = (float*)(ACT + (size_t)NN * GH);  // NN
  float* P        = dinv + NN;                        // NG*64
  int* gstart     = (int*)(P + (size_t)NG * GH);      // NG+1
  int* rowptr     = gstart + NG + 3;                  // NN+1
  int* esrc       = rowptr + NN + 1;                  // NE
  uint32_t* packed= (uint32_t*)(esrc + NE);           // NE
  int* btot       = (int*)(packed + NE);              // NBKT
  int* bcur       = btot + NBKT;                      // NBKT (contiguous w/ btot)
  int* ebase      = bcur + NBKT;                      // NBKT+1

  const int* row = ei;        // edge_index[0] = source
  const int* col = ei + NE;   // edge_index[1] = target (aggregate here)

  // --- bucketed CSR build + dinv + graph starts ---
  k_zero_i<<<cdiv(2 * NBKT, TPB), TPB, 0, stream>>>(btot, 2 * NBKT);  // btot+bcur
  k_bcount<<<BA, TPB, 0, stream>>>(col, btot);
  k_bscan<<<1, 64, 0, stream>>>(btot, ebase);
  k_bscatter<<<BA, TPB, 0, stream>>>(row, col, ebase, bcur, packed);
  k_bbuild<<<NBKT, TPB, 0, stream>>>(packed, ebase, rowptr, dinv, esrc);
  k_gstart<<<cdiv(NG + 1, TPB), TPB, 0, stream>>>(bt, gstart);

  const int gridN = cdiv(NN, TPB / 64);

  // --- layer 1 ---
  k_mm1<<<MMBLK, TPB, 0, stream>>>(x, W1, dinv, HP);
  k_agg<true, false, true><<<gridN, TPB, 0, stream>>>(rowptr, esrc, dinv, (const uint4*)HP, b1, (uint4*)ACT);
  // --- layer 2 ---
  k_mmh<<<MMBLK, TPB, 0, stream>>>(ACT, W2, dinv, HP);
  k_agg<true, false, true><<<gridN, TPB, 0, stream>>>(rowptr, esrc, dinv, (const uint4*)HP, b2, (uint4*)ACT);
  // --- layer 3 ---
  k_mmh<<<MMBLK, TPB, 0, stream>>>(ACT, W3, dinv, HP);
  k_agg<true, false, true><<<gridN, TPB, 0, stream>>>(rowptr, esrc, dinv, (const uint4*)HP, b3, (uint4*)ACT);
  // --- layer 4 (algebraic swap): AGG4 = Â·H3 into HP, no bias/relu ---
  k_agg<false, true, false><<<gridN, TPB, 0, stream>>>(rowptr, esrc, dinv, (const uint4*)ACT, nullptr, (uint4*)HP);

  // --- pool + head ---
  k_pool<<<NG, TPB, 0, stream>>>(HP, gstart, P);
  k_head<<<NG, 64, 0, stream>>>(P, gstart, W4, b4, out);
}

// Round 13
// 308.572 us; speedup vs baseline: 6.1861x; 1.0590x over previous
//
#include <hip/hip_runtime.h>
#include <math.h>
#include <stdint.h>

#define NN 100000
#define NE 1600000
#define GIN 128
#define GH 64
#define GOUT 10
#define NG 512
#define TPB 256
#define MMBLK 1024                  // blocks for MFMA matmuls (4096 waves)
#define NBKT ((NN + 127) >> 7)      // 782 buckets of 128 nodes
#define BA 512                      // blocks for bucket passes
#define CHA ((NE + BA - 1) / BA)    // 3125 edges per block

typedef __attribute__((ext_vector_type(8))) short bf16x8;
typedef __attribute__((ext_vector_type(4))) float f32x4;

// ---- bf16 helpers (RNE pack) ----
__device__ __forceinline__ float bflo(uint32_t u) { return __uint_as_float(u << 16); }
__device__ __forceinline__ float bfhi(uint32_t u) { return __uint_as_float(u & 0xFFFF0000u); }
__device__ __forceinline__ uint32_t f2bf(float f) {
  uint32_t b = __float_as_uint(f);
  return (b + 0x7FFFu + ((b >> 16) & 1u)) >> 16;
}
__device__ __forceinline__ uint32_t pack2(float lo, float hi) { return f2bf(lo) | (f2bf(hi) << 16); }
__device__ __forceinline__ short bfs(float f) { return (short)f2bf(f); }

// gstart[g] = first node index with batch >= g (batch sorted); gstart[NG] = NN
__global__ void k_gstart(const int* __restrict__ batch, int* __restrict__ gstart) {
  int g = blockIdx.x * TPB + threadIdx.x;
  if (g > NG) return;
  int lo = 0, hi = NN;
  while (lo < hi) { int mid = (lo + hi) >> 1; if (batch[mid] < g) lo = mid + 1; else hi = mid; }
  gstart[g] = lo;
}

// ---- bucketed CSR build: NO global atomics anywhere ----
// A1: per-block LDS bucket histogram -> contiguous row of cntm[b][k]
__global__ void k_bcount(const int* __restrict__ col, int* __restrict__ cntm) {
  __shared__ int cnt[NBKT];
  for (int k = threadIdx.x; k < NBKT; k += TPB) cnt[k] = 0;
  __syncthreads();
  int e0 = blockIdx.x * CHA, e1 = min(e0 + CHA, NE);
  for (int e = e0 + threadIdx.x; e < e1; e += TPB)
    atomicAdd(&cnt[col[e] >> 7], 1);
  __syncthreads();
  int* outr = cntm + (size_t)blockIdx.x * NBKT;
  for (int k = threadIdx.x; k < NBKT; k += TPB) outr[k] = cnt[k];
}

// A2: per bucket k, exclusive scan over blocks -> bas[b][k]; total -> btot[k]
__global__ void k_cscan(const int* __restrict__ cntm, int* __restrict__ bas,
                        int* __restrict__ btot) {
  __shared__ int ws[5];
  int k = blockIdx.x;
  int t = threadIdx.x;
  int v0 = cntm[(size_t)(2 * t) * NBKT + k];
  int v1 = cntm[(size_t)(2 * t + 1) * NBKT + k];
  int s = v0 + v1;
  int lane = t & 63, wid = t >> 6;
  int sc = s;
#pragma unroll
  for (int off = 1; off < 64; off <<= 1) {
    int u = __shfl_up(sc, off);
    if (lane >= off) sc += u;
  }
  if (lane == 63) ws[wid] = sc;
  __syncthreads();
  if (t == 0) {
    int a = 0;
    for (int w = 0; w < 4; ++w) { int x = ws[w]; ws[w] = a; a += x; }
    ws[4] = a;
  }
  __syncthreads();
  int excl = sc - s + ws[wid];
  bas[(size_t)(2 * t) * NBKT + k] = excl;
  bas[(size_t)(2 * t + 1) * NBKT + k] = excl + v0;
  if (t == 0) btot[k] = ws[4];
}

// A3: exclusive scan of 782 bucket totals (tiny, serial).
__global__ void k_bscan(const int* __restrict__ btot, int* __restrict__ ebase) {
  if (threadIdx.x == 0) {
    int a = 0;
    for (int k = 0; k < NBKT; ++k) { ebase[k] = a; a += btot[k]; }
    ebase[NBKT] = a;  // == NE
  }
}

// A4: write packed edges (row | colLow<<17) into contiguous bucket regions,
// per-(block,bucket) base precomputed -> LDS cursors only.
__global__ void k_bscatter(const int* __restrict__ row, const int* __restrict__ col,
                           const int* __restrict__ ebase, const int* __restrict__ bas,
                           uint32_t* __restrict__ packed) {
  __shared__ int cur[NBKT];
  __shared__ int base[NBKT];
  const int* basr = bas + (size_t)blockIdx.x * NBKT;
  for (int k = threadIdx.x; k < NBKT; k += TPB) {
    cur[k] = 0;
    base[k] = ebase[k] + basr[k];
  }
  __syncthreads();
  int e0 = blockIdx.x * CHA, e1 = min(e0 + CHA, NE);
  for (int e = e0 + threadIdx.x; e < e1; e += TPB) {
    int c = col[e];
    int k = c >> 7;
    int off = atomicAdd(&cur[k], 1);
    packed[base[k] + off] = (uint32_t)row[e] | ((uint32_t)(c & 127) << 17);
  }
}

// B: one block per bucket — 128-bin LDS hist -> rowptr/dinv + esrc scatter
// (LDS atomics only; writes land in this bucket's contiguous ~8KB esrc window).
__global__ void k_bbuild(const uint32_t* __restrict__ packed, const int* __restrict__ ebase,
                         int* __restrict__ rowptr, float* __restrict__ dinv,
                         int* __restrict__ esrc) {
  __shared__ int hist[128], hptr[128], off[128];
  int bkt = blockIdx.x;
  int s0 = ebase[bkt], s1 = ebase[bkt + 1];
  int n0 = bkt << 7;
  int nloc = min(128, NN - n0);
  for (int k = threadIdx.x; k < 128; k += TPB) { hist[k] = 0; off[k] = 0; }
  __syncthreads();
  for (int i = s0 + threadIdx.x; i < s1; i += TPB)
    atomicAdd(&hist[packed[i] >> 17], 1);
  __syncthreads();
  if (threadIdx.x == 0) {
    int a = 0;
    for (int k = 0; k < 128; ++k) { hptr[k] = a; a += hist[k]; }
  }
  __syncthreads();
  if (threadIdx.x < nloc) {
    int k = threadIdx.x;
    rowptr[n0 + k] = s0 + hptr[k];
    dinv[n0 + k] = rsqrtf((float)hist[k] + 1.0f);  // +1 self-loop
  }
  if (bkt == NBKT - 1 && threadIdx.x == 0) rowptr[NN] = NE;
  for (int i = s0 + threadIdx.x; i < s1; i += TPB) {
    uint32_t u = packed[i];
    int k = (int)(u >> 17);
    int r = atomicAdd(&off[k], 1);
    esrc[s0 + hptr[k] + r] = (int)(u & 0x1FFFFu);
  }
}

// ---- MFMA matmul, layer 1: X f32 [NN,128] @ W1[128,64] -> bf16 Y [NN,64], *dinv ----
__global__ __launch_bounds__(TPB, 1)
void k_mm1(const float* __restrict__ X, const float* __restrict__ W,
           const float* __restrict__ dinv, ushort* __restrict__ Y) {
  int lane = threadIdx.x & 63;
  int wv = blockIdx.x * (TPB / 64) + (threadIdx.x >> 6);
  const int nwv = MMBLK * (TPB / 64);
  int kb = (lane >> 4) * 8;   // k-base within a 32-k tile
  int fcol = lane & 15;       // B col / C col / A row index
  bf16x8 bfr[4][4];
#pragma unroll
  for (int kt = 0; kt < 4; ++kt)
#pragma unroll
    for (int ct = 0; ct < 4; ++ct)
#pragma unroll
      for (int j = 0; j < 8; ++j)
        bfr[kt][ct][j] = bfs(W[(size_t)(kt * 32 + kb + j) * GH + ct * 16 + fcol]);
  const int NT = NN / 16;  // 6250
  for (int t = wv; t < NT; t += nwv) {
    int n0 = t * 16;
    const float* xr = X + (size_t)(n0 + fcol) * GIN;
    f32x4 acc[4] = {{0,0,0,0},{0,0,0,0},{0,0,0,0},{0,0,0,0}};
#pragma unroll
    for (int kt = 0; kt < 4; ++kt) {
      float4 p = *(const float4*)(xr + kt * 32 + kb);
      float4 q = *(const float4*)(xr + kt * 32 + kb + 4);
      bf16x8 a;
      a[0] = bfs(p.x); a[1] = bfs(p.y); a[2] = bfs(p.z); a[3] = bfs(p.w);
      a[4] = bfs(q.x); a[5] = bfs(q.y); a[6] = bfs(q.z); a[7] = bfs(q.w);
#pragma unroll
      for (int ct = 0; ct < 4; ++ct)
        acc[ct] = __builtin_amdgcn_mfma_f32_16x16x32_bf16(a, bfr[kt][ct], acc[ct], 0, 0, 0);
    }
    int rbase = (lane >> 4) * 4;
#pragma unroll
    for (int reg = 0; reg < 4; ++reg) {
      int n = n0 + rbase + reg;
      float d = dinv[n];
#pragma unroll
      for (int ct = 0; ct < 4; ++ct)
        Y[(size_t)n * GH + ct * 16 + fcol] = (ushort)f2bf(acc[ct][reg] * d);
    }
  }
}

// ---- MFMA matmul, layers 2/3: X bf16 [NN,64] @ W[64,64] -> bf16 Y, *dinv ----
__global__ __launch_bounds__(TPB, 1)
void k_mmh(const ushort* __restrict__ X, const float* __restrict__ W,
           const float* __restrict__ dinv, ushort* __restrict__ Y) {
  int lane = threadIdx.x & 63;
  int wv = blockIdx.x * (TPB / 64) + (threadIdx.x >> 6);
  const int nwv = MMBLK * (TPB / 64);
  int kb = (lane >> 4) * 8;
  int fcol = lane & 15;
  bf16x8 bfr[2][4];
#pragma unroll
  for (int kt = 0; kt < 2; ++kt)
#pragma unroll
    for (int ct = 0; ct < 4; ++ct)
#pragma unroll
      for (int j = 0; j < 8; ++j)
        bfr[kt][ct][j] = bfs(W[(size_t)(kt * 32 + kb + j) * GH + ct * 16 + fcol]);
  const int NT = NN / 16;
  for (int t = wv; t < NT; t += nwv) {
    int n0 = t * 16;
    const ushort* xr = X + (size_t)(n0 + fcol) * GH;
    f32x4 acc[4] = {{0,0,0,0},{0,0,0,0},{0,0,0,0},{0,0,0,0}};
#pragma unroll
    for (int kt = 0; kt < 2; ++kt) {
      bf16x8 a = *(const bf16x8*)(xr + kt * 32 + kb);
#pragma unroll
      for (int ct = 0; ct < 4; ++ct)
        acc[ct] = __builtin_amdgcn_mfma_f32_16x16x32_bf16(a, bfr[kt][ct], acc[ct], 0, 0, 0);
    }
    int rbase = (lane >> 4) * 4;
#pragma unroll
    for (int reg = 0; reg < 4; ++reg) {
      int n = n0 + rbase + reg;
      float d = dinv[n];
#pragma unroll
      for (int ct = 0; ct < 4; ++ct)
        Y[(size_t)n * GH + ct * 16 + fcol] = (ushort)f2bf(acc[ct][reg] * d);
    }
  }
}

// One wave per node; 8 groups of 8 lanes; group q handles edges s0+q, s0+q+8, ...
// Each lane loads uint4 = 8 bf16 feats (full 128 B row per 8-lane group = one
// cache line, zero overfetch). acc f32; cross-group shfl reduction.
template<bool RELU, bool SCALE_SRC, bool BIAS>
__global__ void k_agg(const int* __restrict__ rowptr, const int* __restrict__ esrc,
                      const float* __restrict__ dinv, const uint4* __restrict__ hp,
                      const float* __restrict__ bias, uint4* __restrict__ out) {
  int n = blockIdx.x * (TPB / 64) + (threadIdx.x >> 6);
  if (n >= NN) return;
  int lane = threadIdx.x & 63;
  int qid = lane >> 3, fq = lane & 7;
  int s0 = rowptr[n], s1 = rowptr[n + 1];
  float acc[8] = {0.f, 0.f, 0.f, 0.f, 0.f, 0.f, 0.f, 0.f};
  int e = s0 + qid;
  for (; e + 8 < s1; e += 16) {
    int r0 = esrc[e], r1 = esrc[e + 8];
    uint4 v0 = hp[(size_t)r0 * 8 + fq];
    uint4 v1 = hp[(size_t)r1 * 8 + fq];
    float d0 = 1.f, d1 = 1.f;
    if (SCALE_SRC) { d0 = dinv[r0]; d1 = dinv[r1]; }
    acc[0] += bflo(v0.x) * d0; acc[1] += bfhi(v0.x) * d0;
    acc[2] += bflo(v0.y) * d0; acc[3] += bfhi(v0.y) * d0;
    acc[4] += bflo(v0.z) * d0; acc[5] += bfhi(v0.z) * d0;
    acc[6] += bflo(v0.w) * d0; acc[7] += bfhi(v0.w) * d0;
    acc[0] += bflo(v1.x) * d1; acc[1] += bfhi(v1.x) * d1;
    acc[2] += bflo(v1.y) * d1; acc[3] += bfhi(v1.y) * d1;
    acc[4] += bflo(v1.z) * d1; acc[5] += bfhi(v1.z) * d1;
    acc[6] += bflo(v1.w) * d1; acc[7] += bfhi(v1.w) * d1;
  }
  if (e < s1) {
    int r = esrc[e];
    uint4 v = hp[(size_t)r * 8 + fq];
    float d = SCALE_SRC ? dinv[r] : 1.f;
    acc[0] += bflo(v.x) * d; acc[1] += bfhi(v.x) * d;
    acc[2] += bflo(v.y) * d; acc[3] += bfhi(v.y) * d;
    acc[4] += bflo(v.z) * d; acc[5] += bfhi(v.z) * d;
    acc[6] += bflo(v.w) * d; acc[7] += bfhi(v.w) * d;
  }
#pragma unroll
  for (int off = 8; off < 64; off <<= 1) {
#pragma unroll
    for (int i = 0; i < 8; ++i) acc[i] += __shfl_xor(acc[i], off);
  }
  if (qid == 0) {
    float dn = dinv[n];
    uint4 sv = hp[(size_t)n * 8 + fq];
    float sc = SCALE_SRC ? dn : 1.f;
    float r[8];
    r[0] = (acc[0] + bflo(sv.x) * sc) * dn; r[1] = (acc[1] + bfhi(sv.x) * sc) * dn;
    r[2] = (acc[2] + bflo(sv.y) * sc) * dn; r[3] = (acc[3] + bfhi(sv.y) * sc) * dn;
    r[4] = (acc[4] + bflo(sv.z) * sc) * dn; r[5] = (acc[5] + bfhi(sv.z) * sc) * dn;
    r[6] = (acc[6] + bflo(sv.w) * sc) * dn; r[7] = (acc[7] + bfhi(sv.w) * sc) * dn;
    if (BIAS) {
      const float4* b4p = (const float4*)bias;
      float4 bA = b4p[fq * 2], bB = b4p[fq * 2 + 1];
      r[0] += bA.x; r[1] += bA.y; r[2] += bA.z; r[3] += bA.w;
      r[4] += bB.x; r[5] += bB.y; r[6] += bB.z; r[7] += bB.w;
    }
    if (RELU) {
#pragma unroll
      for (int i = 0; i < 8; ++i) r[i] = fmaxf(r[i], 0.f);
    }
    uint4 o;
    o.x = pack2(r[0], r[1]); o.y = pack2(r[2], r[3]);
    o.z = pack2(r[4], r[5]); o.w = pack2(r[6], r[7]);
    out[(size_t)n * 8 + fq] = o;
  }
}

// per-graph segmented sum over sorted batch; input flat [NN][64]
__global__ void k_pool(const ushort* __restrict__ agg4, const int* __restrict__ gstart,
                       float* __restrict__ P) {
  __shared__ float part[4][GH];
  int g = blockIdx.x;
  int f = threadIdx.x & 63, r = threadIdx.x >> 6;
  int a = gstart[g], b = gstart[g + 1];
  float acc = 0.f;
  for (int n = a + r; n < b; n += 4)
    acc += __uint_as_float(((uint32_t)agg4[(size_t)n * GH + f]) << 16);
  part[r][f] = acc;
  __syncthreads();
  if (r == 0) P[(size_t)g * GH + f] = part[0][f] + part[1][f] + part[2][f] + part[3][f];
}

__global__ void k_head(const float* __restrict__ P, const int* __restrict__ gstart,
                       const float* __restrict__ W4, const float* __restrict__ b4,
                       float* __restrict__ out) {
  int g = blockIdx.x;
  int lane = threadIdx.x;  // 64
  float c = fmaxf((float)(gstart[g + 1] - gstart[g]), 1.0f);
  float p = P[(size_t)g * GH + lane] / c;
  float t[GOUT];
#pragma unroll
  for (int j = 0; j < GOUT; ++j) {
    float r = p * W4[lane * GOUT + j];
#pragma unroll
    for (int off = 1; off < 64; off <<= 1) r += __shfl_xor(r, off);
    t[j] = r + b4[j];
  }
  if (lane == 0) {
    float mx = -1e30f;
#pragma unroll
    for (int j = 0; j < GOUT; ++j) mx = fmaxf(mx, t[j]);
    float sum = 0.f;
#pragma unroll
    for (int j = 0; j < GOUT; ++j) sum += expf(t[j] - mx);
    float lse = mx + logf(sum);
#pragma unroll
    for (int j = 0; j < GOUT; ++j) out[(size_t)g * GOUT + j] = t[j] - lse;
  }
}

static inline int cdiv(long a, long b) { return (int)((a + b - 1) / b); }

extern "C" void kernel_launch(void* const* d_in, const int* in_sizes, int n_in,
                              void* d_out, int out_size, void* d_ws, size_t ws_size,
                              hipStream_t stream) {
  const float* x  = (const float*)d_in[0];
  const int*   ei = (const int*)d_in[1];
  const int*   bt = (const int*)d_in[2];
  const float* W1 = (const float*)d_in[3];
  const float* b1 = (const float*)d_in[4];
  const float* W2 = (const float*)d_in[5];
  const float* b2 = (const float*)d_in[6];
  const float* W3 = (const float*)d_in[7];
  const float* b3 = (const float*)d_in[8];
  const float* W4 = (const float*)d_in[9];
  const float* b4 = (const float*)d_in[10];
  float* out = (float*)d_out;

  ushort* HP      = (ushort*)d_ws;                    // NN*64 bf16
  ushort* ACT     = HP + (size_t)NN * GH;             // NN*64 bf16
  float* dinv     = (float*)(ACT + (size_t)NN * GH);  // NN
  float* P        = dinv + NN;                        // NG*64
  int* gstart     = (int*)(P + (size_t)NG * GH);      // NG+1
  int* rowptr     = gstart + NG + 3;                  // NN+1
  int* esrc       = rowptr + NN + 1;                  // NE
  uint32_t* packed= (uint32_t*)(esrc + NE);           // NE
  int* cntm       = (int*)(packed + NE);              // BA*NBKT
  int* bas        = cntm + (size_t)BA * NBKT;         // BA*NBKT
  int* btot       = bas + (size_t)BA * NBKT;          // NBKT
  int* ebase      = btot + NBKT;                      // NBKT+1

  const int* row = ei;        // edge_index[0] = source
  const int* col = ei + NE;   // edge_index[1] = target (aggregate here)

  // --- bucketed CSR build (atomic-free) + dinv + graph starts ---
  k_bcount<<<BA, TPB, 0, stream>>>(col, cntm);
  k_cscan<<<NBKT, TPB, 0, stream>>>(cntm, bas, btot);
  k_bscan<<<1, 64, 0, stream>>>(btot, ebase);
  k_bscatter<<<BA, TPB, 0, stream>>>(row, col, ebase, bas, packed);
  k_bbuild<<<NBKT, TPB, 0, stream>>>(packed, ebase, rowptr, dinv, esrc);
  k_gstart<<<cdiv(NG + 1, TPB), TPB, 0, stream>>>(bt, gstart);

  const int gridN = cdiv(NN, TPB / 64);

  // --- layer 1 ---
  k_mm1<<<MMBLK, TPB, 0, stream>>>(x, W1, dinv, HP);
  k_agg<true, false, true><<<gridN, TPB, 0, stream>>>(rowptr, esrc, dinv, (const uint4*)HP, b1, (uint4*)ACT);
  // --- layer 2 ---
  k_mmh<<<MMBLK, TPB, 0, stream>>>(ACT, W2, dinv, HP);
  k_agg<true, false, true><<<gridN, TPB, 0, stream>>>(rowptr, esrc, dinv, (const uint4*)HP, b2, (uint4*)ACT);
  // --- layer 3 ---
  k_mmh<<<MMBLK, TPB, 0, stream>>>(ACT, W3, dinv, HP);
  k_agg<true, false, true><<<gridN, TPB, 0, stream>>>(rowptr, esrc, dinv, (const uint4*)HP, b3, (uint4*)ACT);
  // --- layer 4 (algebraic swap): AGG4 = Â·H3 into HP, no bias/relu ---
  k_agg<false, true, false><<<gridN, TPB, 0, stream>>>(rowptr, esrc, dinv, (const uint4*)ACT, nullptr, (uint4*)HP);

  // --- pool + head ---
  k_pool<<<NG, TPB, 0, stream>>>(HP, gstart, P);
  k_head<<<NG, 64, 0, stream>>>(P, gstart, W4, b4, out);
}

// Round 14
// 259.715 us; speedup vs baseline: 7.3498x; 1.1881x over previous
//
#include <hip/hip_runtime.h>
#include <math.h>
#include <stdint.h>

#define NN 100000
#define NE 1600000
#define GIN 128
#define GH 64
#define GOUT 10
#define NG 512
#define TPB 256
#define MMBLK 1024                  // blocks for MFMA matmuls (4096 waves)
#define NBKT ((NN + 127) >> 7)      // 782 buckets of 128 nodes
#define BA 512                      // blocks for bucket passes
#define CHA ((NE + BA - 1) / BA)    // 3125 edges per block

typedef __attribute__((ext_vector_type(8))) short bf16x8;
typedef __attribute__((ext_vector_type(4))) float f32x4;

// ---- bf16 helpers (RNE pack) ----
__device__ __forceinline__ float bflo(uint32_t u) { return __uint_as_float(u << 16); }
__device__ __forceinline__ float bfhi(uint32_t u) { return __uint_as_float(u & 0xFFFF0000u); }
__device__ __forceinline__ uint32_t f2bf(float f) {
  uint32_t b = __float_as_uint(f);
  return (b + 0x7FFFu + ((b >> 16) & 1u)) >> 16;
}
__device__ __forceinline__ uint32_t pack2(float lo, float hi) { return f2bf(lo) | (f2bf(hi) << 16); }
__device__ __forceinline__ short bfs(float f) { return (short)f2bf(f); }

// gstart[g] = first node index with batch >= g (batch sorted); gstart[NG] = NN
__global__ void k_gstart(const int* __restrict__ batch, int* __restrict__ gstart) {
  int g = blockIdx.x * TPB + threadIdx.x;
  if (g > NG) return;
  int lo = 0, hi = NN;
  while (lo < hi) { int mid = (lo + hi) >> 1; if (batch[mid] < g) lo = mid + 1; else hi = mid; }
  gstart[g] = lo;
}

// ---- bucketed CSR build: NO global atomics anywhere ----
// A1: per-block LDS bucket histogram -> contiguous row of cntm[b][k]
__global__ void k_bcount(const int* __restrict__ col, int* __restrict__ cntm) {
  __shared__ int cnt[NBKT];
  for (int k = threadIdx.x; k < NBKT; k += TPB) cnt[k] = 0;
  __syncthreads();
  int e0 = blockIdx.x * CHA, e1 = min(e0 + CHA, NE);
  for (int e = e0 + threadIdx.x; e < e1; e += TPB)
    atomicAdd(&cnt[col[e] >> 7], 1);
  __syncthreads();
  int* outr = cntm + (size_t)blockIdx.x * NBKT;
  for (int k = threadIdx.x; k < NBKT; k += TPB) outr[k] = cnt[k];
}

// A2: per bucket k, exclusive scan over blocks -> bas[b][k]; total -> btot[k]
__global__ void k_cscan(const int* __restrict__ cntm, int* __restrict__ bas,
                        int* __restrict__ btot) {
  __shared__ int ws[5];
  int k = blockIdx.x;
  int t = threadIdx.x;
  int v0 = cntm[(size_t)(2 * t) * NBKT + k];
  int v1 = cntm[(size_t)(2 * t + 1) * NBKT + k];
  int s = v0 + v1;
  int lane = t & 63, wid = t >> 6;
  int sc = s;
#pragma unroll
  for (int off = 1; off < 64; off <<= 1) {
    int u = __shfl_up(sc, off);
    if (lane >= off) sc += u;
  }
  if (lane == 63) ws[wid] = sc;
  __syncthreads();
  if (t == 0) {
    int a = 0;
    for (int w = 0; w < 4; ++w) { int x = ws[w]; ws[w] = a; a += x; }
    ws[4] = a;
  }
  __syncthreads();
  int excl = sc - s + ws[wid];
  bas[(size_t)(2 * t) * NBKT + k] = excl;
  bas[(size_t)(2 * t + 1) * NBKT + k] = excl + v0;
  if (t == 0) btot[k] = ws[4];
}

// A3: exclusive scan of 782 bucket totals (tiny, serial).
__global__ void k_bscan(const int* __restrict__ btot, int* __restrict__ ebase) {
  if (threadIdx.x == 0) {
    int a = 0;
    for (int k = 0; k < NBKT; ++k) { ebase[k] = a; a += btot[k]; }
    ebase[NBKT] = a;  // == NE
  }
}

// A4: write packed edges (row | colLow<<17) into contiguous bucket regions,
// per-(block,bucket) base precomputed -> LDS cursors only.
__global__ void k_bscatter(const int* __restrict__ row, const int* __restrict__ col,
                           const int* __restrict__ ebase, const int* __restrict__ bas,
                           uint32_t* __restrict__ packed) {
  __shared__ int cur[NBKT];
  __shared__ int base[NBKT];
  const int* basr = bas + (size_t)blockIdx.x * NBKT;
  for (int k = threadIdx.x; k < NBKT; k += TPB) {
    cur[k] = 0;
    base[k] = ebase[k] + basr[k];
  }
  __syncthreads();
  int e0 = blockIdx.x * CHA, e1 = min(e0 + CHA, NE);
  for (int e = e0 + threadIdx.x; e < e1; e += TPB) {
    int c = col[e];
    int k = c >> 7;
    int off = atomicAdd(&cur[k], 1);
    packed[base[k] + off] = (uint32_t)row[e] | ((uint32_t)(c & 127) << 17);
  }
}

// B: one block per bucket — 128-bin LDS hist -> rowptr/dinv + esrc scatter
// (LDS atomics only; writes land in this bucket's contiguous ~8KB esrc window).
__global__ void k_bbuild(const uint32_t* __restrict__ packed, const int* __restrict__ ebase,
                         int* __restrict__ rowptr, float* __restrict__ dinv,
                         int* __restrict__ esrc) {
  __shared__ int hist[128], hptr[128], off[128];
  int bkt = blockIdx.x;
  int s0 = ebase[bkt], s1 = ebase[bkt + 1];
  int n0 = bkt << 7;
  int nloc = min(128, NN - n0);
  for (int k = threadIdx.x; k < 128; k += TPB) { hist[k] = 0; off[k] = 0; }
  __syncthreads();
  for (int i = s0 + threadIdx.x; i < s1; i += TPB)
    atomicAdd(&hist[packed[i] >> 17], 1);
  __syncthreads();
  if (threadIdx.x == 0) {
    int a = 0;
    for (int k = 0; k < 128; ++k) { hptr[k] = a; a += hist[k]; }
  }
  __syncthreads();
  if (threadIdx.x < nloc) {
    int k = threadIdx.x;
    rowptr[n0 + k] = s0 + hptr[k];
    dinv[n0 + k] = rsqrtf((float)hist[k] + 1.0f);  // +1 self-loop
  }
  if (bkt == NBKT - 1 && threadIdx.x == 0) rowptr[NN] = NE;
  for (int i = s0 + threadIdx.x; i < s1; i += TPB) {
    uint32_t u = packed[i];
    int k = (int)(u >> 17);
    int r = atomicAdd(&off[k], 1);
    esrc[s0 + hptr[k] + r] = (int)(u & 0x1FFFFu);
  }
}

// ---- MFMA matmul, layer 1: X f32 [NN,128] @ W1[128,64] -> bf16 Y [NN,64], *dinv ----
__global__ __launch_bounds__(TPB, 1)
void k_mm1(const float* __restrict__ X, const float* __restrict__ W,
           const float* __restrict__ dinv, ushort* __restrict__ Y) {
  int lane = threadIdx.x & 63;
  int wv = blockIdx.x * (TPB / 64) + (threadIdx.x >> 6);
  const int nwv = MMBLK * (TPB / 64);
  int kb = (lane >> 4) * 8;   // k-base within a 32-k tile
  int fcol = lane & 15;       // B col / C col / A row index
  bf16x8 bfr[4][4];
#pragma unroll
  for (int kt = 0; kt < 4; ++kt)
#pragma unroll
    for (int ct = 0; ct < 4; ++ct)
#pragma unroll
      for (int j = 0; j < 8; ++j)
        bfr[kt][ct][j] = bfs(W[(size_t)(kt * 32 + kb + j) * GH + ct * 16 + fcol]);
  const int NT = NN / 16;  // 6250
  for (int t = wv; t < NT; t += nwv) {
    int n0 = t * 16;
    const float* xr = X + (size_t)(n0 + fcol) * GIN;
    f32x4 acc[4] = {{0,0,0,0},{0,0,0,0},{0,0,0,0},{0,0,0,0}};
#pragma unroll
    for (int kt = 0; kt < 4; ++kt) {
      float4 p = *(const float4*)(xr + kt * 32 + kb);
      float4 q = *(const float4*)(xr + kt * 32 + kb + 4);
      bf16x8 a;
      a[0] = bfs(p.x); a[1] = bfs(p.y); a[2] = bfs(p.z); a[3] = bfs(p.w);
      a[4] = bfs(q.x); a[5] = bfs(q.y); a[6] = bfs(q.z); a[7] = bfs(q.w);
#pragma unroll
      for (int ct = 0; ct < 4; ++ct)
        acc[ct] = __builtin_amdgcn_mfma_f32_16x16x32_bf16(a, bfr[kt][ct], acc[ct], 0, 0, 0);
    }
    int rbase = (lane >> 4) * 4;
#pragma unroll
    for (int reg = 0; reg < 4; ++reg) {
      int n = n0 + rbase + reg;
      float d = dinv[n];
#pragma unroll
      for (int ct = 0; ct < 4; ++ct)
        Y[(size_t)n * GH + ct * 16 + fcol] = (ushort)f2bf(acc[ct][reg] * d);
    }
  }
}

// ---- MFMA matmul, layers 2/3: X bf16 [NN,64] @ W[64,64] -> bf16 Y, *dinv ----
__global__ __launch_bounds__(TPB, 1)
void k_mmh(const ushort* __restrict__ X, const float* __restrict__ W,
           const float* __restrict__ dinv, ushort* __restrict__ Y) {
  int lane = threadIdx.x & 63;
  int wv = blockIdx.x * (TPB / 64) + (threadIdx.x >> 6);
  const int nwv = MMBLK * (TPB / 64);
  int kb = (lane >> 4) * 8;
  int fcol = lane & 15;
  bf16x8 bfr[2][4];
#pragma unroll
  for (int kt = 0; kt < 2; ++kt)
#pragma unroll
    for (int ct = 0; ct < 4; ++ct)
#pragma unroll
      for (int j = 0; j < 8; ++j)
        bfr[kt][ct][j] = bfs(W[(size_t)(kt * 32 + kb + j) * GH + ct * 16 + fcol]);
  const int NT = NN / 16;
  for (int t = wv; t < NT; t += nwv) {
    int n0 = t * 16;
    const ushort* xr = X + (size_t)(n0 + fcol) * GH;
    f32x4 acc[4] = {{0,0,0,0},{0,0,0,0},{0,0,0,0},{0,0,0,0}};
#pragma unroll
    for (int kt = 0; kt < 2; ++kt) {
      bf16x8 a = *(const bf16x8*)(xr + kt * 32 + kb);
#pragma unroll
      for (int ct = 0; ct < 4; ++ct)
        acc[ct] = __builtin_amdgcn_mfma_f32_16x16x32_bf16(a, bfr[kt][ct], acc[ct], 0, 0, 0);
    }
    int rbase = (lane >> 4) * 4;
#pragma unroll
    for (int reg = 0; reg < 4; ++reg) {
      int n = n0 + rbase + reg;
      float d = dinv[n];
#pragma unroll
      for (int ct = 0; ct < 4; ++ct)
        Y[(size_t)n * GH + ct * 16 + fcol] = (ushort)f2bf(acc[ct][reg] * d);
    }
  }
}

// Aggregation v3: 8 nodes per wave, 8 lanes per node (lane fq owns feats
// fq*8..fq*8+7 across the node's WHOLE edge list). Zero cross-lane reduce;
// all 64 lanes compute and write. Unroll-4 -> 4 gathers in flight per lane.
template<bool RELU, bool SCALE_SRC, bool BIAS>
__global__ void k_agg(const int* __restrict__ rowptr, const int* __restrict__ esrc,
                      const float* __restrict__ dinv, const uint4* __restrict__ hp,
                      const float* __restrict__ bias, uint4* __restrict__ out) {
  int wv = blockIdx.x * (TPB / 64) + (threadIdx.x >> 6);
  int lane = threadIdx.x & 63;
  int n = wv * 8 + (lane >> 3);
  if (n >= NN) return;
  int fq = lane & 7;
  int s0 = rowptr[n], s1 = rowptr[n + 1];
  float acc[8] = {0.f, 0.f, 0.f, 0.f, 0.f, 0.f, 0.f, 0.f};
#define ACC8(v, d)                                             \
  acc[0] += bflo((v).x) * (d); acc[1] += bfhi((v).x) * (d);    \
  acc[2] += bflo((v).y) * (d); acc[3] += bfhi((v).y) * (d);    \
  acc[4] += bflo((v).z) * (d); acc[5] += bfhi((v).z) * (d);    \
  acc[6] += bflo((v).w) * (d); acc[7] += bfhi((v).w) * (d);
  int e = s0;
  for (; e + 3 < s1; e += 4) {
    int r0 = esrc[e], r1 = esrc[e + 1], r2 = esrc[e + 2], r3 = esrc[e + 3];
    uint4 v0 = hp[(size_t)r0 * 8 + fq];
    uint4 v1 = hp[(size_t)r1 * 8 + fq];
    uint4 v2 = hp[(size_t)r2 * 8 + fq];
    uint4 v3 = hp[(size_t)r3 * 8 + fq];
    float d0 = 1.f, d1 = 1.f, d2 = 1.f, d3 = 1.f;
    if (SCALE_SRC) { d0 = dinv[r0]; d1 = dinv[r1]; d2 = dinv[r2]; d3 = dinv[r3]; }
    ACC8(v0, d0) ACC8(v1, d1) ACC8(v2, d2) ACC8(v3, d3)
  }
  for (; e < s1; ++e) {
    int r = esrc[e];
    uint4 v = hp[(size_t)r * 8 + fq];
    float d = SCALE_SRC ? dinv[r] : 1.f;
    ACC8(v, d)
  }
#undef ACC8
  float dn = dinv[n];
  uint4 sv = hp[(size_t)n * 8 + fq];
  float sc = SCALE_SRC ? dn : 1.f;
  float r8[8];
  r8[0] = (acc[0] + bflo(sv.x) * sc) * dn; r8[1] = (acc[1] + bfhi(sv.x) * sc) * dn;
  r8[2] = (acc[2] + bflo(sv.y) * sc) * dn; r8[3] = (acc[3] + bfhi(sv.y) * sc) * dn;
  r8[4] = (acc[4] + bflo(sv.z) * sc) * dn; r8[5] = (acc[5] + bfhi(sv.z) * sc) * dn;
  r8[6] = (acc[6] + bflo(sv.w) * sc) * dn; r8[7] = (acc[7] + bfhi(sv.w) * sc) * dn;
  if (BIAS) {
    const float4* b4p = (const float4*)bias;
    float4 bA = b4p[fq * 2], bB = b4p[fq * 2 + 1];
    r8[0] += bA.x; r8[1] += bA.y; r8[2] += bA.z; r8[3] += bA.w;
    r8[4] += bB.x; r8[5] += bB.y; r8[6] += bB.z; r8[7] += bB.w;
  }
  if (RELU) {
#pragma unroll
    for (int i = 0; i < 8; ++i) r8[i] = fmaxf(r8[i], 0.f);
  }
  uint4 o;
  o.x = pack2(r8[0], r8[1]); o.y = pack2(r8[2], r8[3]);
  o.z = pack2(r8[4], r8[5]); o.w = pack2(r8[6], r8[7]);
  out[(size_t)n * 8 + fq] = o;
}

// per-graph segmented sum over sorted batch; input flat [NN][64]
__global__ void k_pool(const ushort* __restrict__ agg4, const int* __restrict__ gstart,
                       float* __restrict__ P) {
  __shared__ float part[4][GH];
  int g = blockIdx.x;
  int f = threadIdx.x & 63, r = threadIdx.x >> 6;
  int a = gstart[g], b = gstart[g + 1];
  float acc = 0.f;
  for (int n = a + r; n < b; n += 4)
    acc += __uint_as_float(((uint32_t)agg4[(size_t)n * GH + f]) << 16);
  part[r][f] = acc;
  __syncthreads();
  if (r == 0) P[(size_t)g * GH + f] = part[0][f] + part[1][f] + part[2][f] + part[3][f];
}

__global__ void k_head(const float* __restrict__ P, const int* __restrict__ gstart,
                       const float* __restrict__ W4, const float* __restrict__ b4,
                       float* __restrict__ out) {
  int g = blockIdx.x;
  int lane = threadIdx.x;  // 64
  float c = fmaxf((float)(gstart[g + 1] - gstart[g]), 1.0f);
  float p = P[(size_t)g * GH + lane] / c;
  float t[GOUT];
#pragma unroll
  for (int j = 0; j < GOUT; ++j) {
    float r = p * W4[lane * GOUT + j];
#pragma unroll
    for (int off = 1; off < 64; off <<= 1) r += __shfl_xor(r, off);
    t[j] = r + b4[j];
  }
  if (lane == 0) {
    float mx = -1e30f;
#pragma unroll
    for (int j = 0; j < GOUT; ++j) mx = fmaxf(mx, t[j]);
    float sum = 0.f;
#pragma unroll
    for (int j = 0; j < GOUT; ++j) sum += expf(t[j] - mx);
    float lse = mx + logf(sum);
#pragma unroll
    for (int j = 0; j < GOUT; ++j) out[(size_t)g * GOUT + j] = t[j] - lse;
  }
}

static inline int cdiv(long a, long b) { return (int)((a + b - 1) / b); }

extern "C" void kernel_launch(void* const* d_in, const int* in_sizes, int n_in,
                              void* d_out, int out_size, void* d_ws, size_t ws_size,
                              hipStream_t stream) {
  const float* x  = (const float*)d_in[0];
  const int*   ei = (const int*)d_in[1];
  const int*   bt = (const int*)d_in[2];
  const float* W1 = (const float*)d_in[3];
  const float* b1 = (const float*)d_in[4];
  const float* W2 = (const float*)d_in[5];
  const float* b2 = (const float*)d_in[6];
  const float* W3 = (const float*)d_in[7];
  const float* b3 = (const float*)d_in[8];
  const float* W4 = (const float*)d_in[9];
  const float* b4 = (const float*)d_in[10];
  float* out = (float*)d_out;

  ushort* HP      = (ushort*)d_ws;                    // NN*64 bf16
  ushort* ACT     = HP + (size_t)NN * GH;             // NN*64 bf16
  float* dinv     = (float*)(ACT + (size_t)NN * GH);  // NN
  float* P        = dinv + NN;                        // NG*64
  int* gstart     = (int*)(P + (size_t)NG * GH);      // NG+1
  int* rowptr     = gstart + NG + 3;                  // NN+1
  int* esrc       = rowptr + NN + 1;                  // NE
  uint32_t* packed= (uint32_t*)(esrc + NE);           // NE
  int* cntm       = (int*)(packed + NE);              // BA*NBKT
  int* bas        = cntm + (size_t)BA * NBKT;         // BA*NBKT
  int* btot       = bas + (size_t)BA * NBKT;          // NBKT
  int* ebase      = btot + NBKT;                      // NBKT+1

  const int* row = ei;        // edge_index[0] = source
  const int* col = ei + NE;   // edge_index[1] = target (aggregate here)

  // --- bucketed CSR build (atomic-free) + dinv + graph starts ---
  k_bcount<<<BA, TPB, 0, stream>>>(col, cntm);
  k_cscan<<<NBKT, TPB, 0, stream>>>(cntm, bas, btot);
  k_bscan<<<1, 64, 0, stream>>>(btot, ebase);
  k_bscatter<<<BA, TPB, 0, stream>>>(row, col, ebase, bas, packed);
  k_bbuild<<<NBKT, TPB, 0, stream>>>(packed, ebase, rowptr, dinv, esrc);
  k_gstart<<<cdiv(NG + 1, TPB), TPB, 0, stream>>>(bt, gstart);

  const int gridA = cdiv(NN, (TPB / 64) * 8);  // 8 nodes per wave

  // --- layer 1 ---
  k_mm1<<<MMBLK, TPB, 0, stream>>>(x, W1, dinv, HP);
  k_agg<true, false, true><<<gridA, TPB, 0, stream>>>(rowptr, esrc, dinv, (const uint4*)HP, b1, (uint4*)ACT);
  // --- layer 2 ---
  k_mmh<<<MMBLK, TPB, 0, stream>>>(ACT, W2, dinv, HP);
  k_agg<true, false, true><<<gridA, TPB, 0, stream>>>(rowptr, esrc, dinv, (const uint4*)HP, b2, (uint4*)ACT);
  // --- layer 3 ---
  k_mmh<<<MMBLK, TPB, 0, stream>>>(ACT, W3, dinv, HP);
  k_agg<true, false, true><<<gridA, TPB, 0, stream>>>(rowptr, esrc, dinv, (const uint4*)HP, b3, (uint4*)ACT);
  // --- layer 4 (algebraic swap): AGG4 = Â·H3 into HP, no bias/relu ---
  k_agg<false, true, false><<<gridA, TPB, 0, stream>>>(rowptr, esrc, dinv, (const uint4*)ACT, nullptr, (uint4*)HP);

  // --- pool + head ---
  k_pool<<<NG, TPB, 0, stream>>>(HP, gstart, P);
  k_head<<<NG, 64, 0, stream>>>(P, gstart, W4, b4, out);
}

// Round 15
// 246.853 us; speedup vs baseline: 7.7328x; 1.0521x over previous
//
#include <hip/hip_runtime.h>
#include <math.h>
#include <stdint.h>

#define NN 100000
#define NE 1600000
#define GIN 128
#define GH 64
#define GOUT 10
#define NG 512
#define TPB 256
#define MMBLK 1024                  // blocks for MFMA matmuls (4096 waves)
#define NBKT ((NN + 127) >> 7)      // 782 buckets of 128 nodes
#define BA 250                      // blocks for bucket passes
#define CHA 6400                    // edges per block (BA*CHA == NE, 16B aligned)

typedef __attribute__((ext_vector_type(8))) short bf16x8;
typedef __attribute__((ext_vector_type(4))) float f32x4;

// ---- bf16 helpers (RNE pack) ----
__device__ __forceinline__ float bflo(uint32_t u) { return __uint_as_float(u << 16); }
__device__ __forceinline__ float bfhi(uint32_t u) { return __uint_as_float(u & 0xFFFF0000u); }
__device__ __forceinline__ uint32_t f2bf(float f) {
  uint32_t b = __float_as_uint(f);
  return (b + 0x7FFFu + ((b >> 16) & 1u)) >> 16;
}
__device__ __forceinline__ uint32_t pack2(float lo, float hi) { return f2bf(lo) | (f2bf(hi) << 16); }
__device__ __forceinline__ short bfs(float f) { return (short)f2bf(f); }

// ---- bucketed CSR build: NO global atomics anywhere ----
// A1: per-block LDS bucket histogram -> contiguous row of cntm[b][k]
__global__ void k_bcount(const int* __restrict__ col, int* __restrict__ cntm) {
  __shared__ int cnt[NBKT];
  for (int k = threadIdx.x; k < NBKT; k += TPB) cnt[k] = 0;
  __syncthreads();
  const int4* c4 = (const int4*)(col + (size_t)blockIdx.x * CHA);
  for (int i = threadIdx.x; i < CHA / 4; i += TPB) {
    int4 v = c4[i];
    atomicAdd(&cnt[v.x >> 7], 1);
    atomicAdd(&cnt[v.y >> 7], 1);
    atomicAdd(&cnt[v.z >> 7], 1);
    atomicAdd(&cnt[v.w >> 7], 1);
  }
  __syncthreads();
  int* outr = cntm + (size_t)blockIdx.x * NBKT;
  for (int k = threadIdx.x; k < NBKT; k += TPB) outr[k] = cnt[k];
}

// A2: per bucket k, exclusive scan over BA block rows -> bas[b][k]; total -> btot[k]
__global__ void k_cscan(const int* __restrict__ cntm, int* __restrict__ bas,
                        int* __restrict__ btot) {
  __shared__ int ws[5];
  int k = blockIdx.x;
  int t = threadIdx.x;
  int v = (t < BA) ? cntm[(size_t)t * NBKT + k] : 0;
  int lane = t & 63, wid = t >> 6;
  int sc = v;
#pragma unroll
  for (int off = 1; off < 64; off <<= 1) {
    int u = __shfl_up(sc, off);
    if (lane >= off) sc += u;
  }
  if (lane == 63) ws[wid] = sc;
  __syncthreads();
  if (t == 0) {
    int a = 0;
    for (int w = 0; w < 4; ++w) { int x = ws[w]; ws[w] = a; a += x; }
  }
  __syncthreads();
  int excl = sc - v + ws[wid];
  if (t < BA) bas[(size_t)t * NBKT + k] = excl;
  if (t == BA - 1) btot[k] = excl + v;
}

// A3: exclusive scan of 782 bucket totals (tiny, serial).
__global__ void k_bscan(const int* __restrict__ btot, int* __restrict__ ebase) {
  if (threadIdx.x == 0) {
    int a = 0;
    for (int k = 0; k < NBKT; ++k) { ebase[k] = a; a += btot[k]; }
    ebase[NBKT] = a;  // == NE
  }
}

// A4: write packed edges (row | colLow<<17) into contiguous bucket regions,
// per-(block,bucket) base precomputed -> LDS cursors only.
__global__ void k_bscatter(const int* __restrict__ row, const int* __restrict__ col,
                           const int* __restrict__ ebase, const int* __restrict__ bas,
                           uint32_t* __restrict__ packed) {
  __shared__ int cur[NBKT];
  __shared__ int base[NBKT];
  const int* basr = bas + (size_t)blockIdx.x * NBKT;
  for (int k = threadIdx.x; k < NBKT; k += TPB) {
    cur[k] = 0;
    base[k] = ebase[k] + basr[k];
  }
  __syncthreads();
  const int4* c4 = (const int4*)(col + (size_t)blockIdx.x * CHA);
  const int4* r4 = (const int4*)(row + (size_t)blockIdx.x * CHA);
  for (int i = threadIdx.x; i < CHA / 4; i += TPB) {
    int4 c = c4[i];
    int4 r = r4[i];
#define PUT(cc, rr) {                                            \
    int k = (cc) >> 7;                                           \
    int off = atomicAdd(&cur[k], 1);                             \
    packed[base[k] + off] = (uint32_t)(rr) | ((uint32_t)((cc) & 127) << 17); }
    PUT(c.x, r.x) PUT(c.y, r.y) PUT(c.z, r.z) PUT(c.w, r.w)
#undef PUT
  }
}

// B: one block per bucket — 128-bin LDS hist -> rowptr/dinv + esrc scatter
// (LDS atomics only; writes land in this bucket's contiguous ~8KB esrc window).
__global__ void k_bbuild(const uint32_t* __restrict__ packed, const int* __restrict__ ebase,
                         int* __restrict__ rowptr, float* __restrict__ dinv,
                         int* __restrict__ esrc) {
  __shared__ int hist[128], hptr[128], off[128];
  int bkt = blockIdx.x;
  int s0 = ebase[bkt], s1 = ebase[bkt + 1];
  int n0 = bkt << 7;
  int nloc = min(128, NN - n0);
  for (int k = threadIdx.x; k < 128; k += TPB) { hist[k] = 0; off[k] = 0; }
  __syncthreads();
  for (int i = s0 + threadIdx.x; i < s1; i += TPB)
    atomicAdd(&hist[packed[i] >> 17], 1);
  __syncthreads();
  if (threadIdx.x == 0) {
    int a = 0;
    for (int k = 0; k < 128; ++k) { hptr[k] = a; a += hist[k]; }
  }
  __syncthreads();
  if (threadIdx.x < nloc) {
    int k = threadIdx.x;
    rowptr[n0 + k] = s0 + hptr[k];
    dinv[n0 + k] = rsqrtf((float)hist[k] + 1.0f);  // +1 self-loop
  }
  if (bkt == NBKT - 1 && threadIdx.x == 0) rowptr[NN] = NE;
  for (int i = s0 + threadIdx.x; i < s1; i += TPB) {
    uint32_t u = packed[i];
    int k = (int)(u >> 17);
    int r = atomicAdd(&off[k], 1);
    esrc[s0 + hptr[k] + r] = (int)(u & 0x1FFFFu);
  }
}

// ---- MFMA matmul, layer 1: X f32 [NN,128] @ W1[128,64] -> bf16 Y [NN,64], *dinv ----
__global__ __launch_bounds__(TPB, 1)
void k_mm1(const float* __restrict__ X, const float* __restrict__ W,
           const float* __restrict__ dinv, ushort* __restrict__ Y) {
  int lane = threadIdx.x & 63;
  int wv = blockIdx.x * (TPB / 64) + (threadIdx.x >> 6);
  const int nwv = MMBLK * (TPB / 64);
  int kb = (lane >> 4) * 8;   // k-base within a 32-k tile
  int fcol = lane & 15;       // B col / C col / A row index
  bf16x8 bfr[4][4];
#pragma unroll
  for (int kt = 0; kt < 4; ++kt)
#pragma unroll
    for (int ct = 0; ct < 4; ++ct)
#pragma unroll
      for (int j = 0; j < 8; ++j)
        bfr[kt][ct][j] = bfs(W[(size_t)(kt * 32 + kb + j) * GH + ct * 16 + fcol]);
  const int NT = NN / 16;  // 6250
  for (int t = wv; t < NT; t += nwv) {
    int n0 = t * 16;
    const float* xr = X + (size_t)(n0 + fcol) * GIN;
    f32x4 acc[4] = {{0,0,0,0},{0,0,0,0},{0,0,0,0},{0,0,0,0}};
#pragma unroll
    for (int kt = 0; kt < 4; ++kt) {
      float4 p = *(const float4*)(xr + kt * 32 + kb);
      float4 q = *(const float4*)(xr + kt * 32 + kb + 4);
      bf16x8 a;
      a[0] = bfs(p.x); a[1] = bfs(p.y); a[2] = bfs(p.z); a[3] = bfs(p.w);
      a[4] = bfs(q.x); a[5] = bfs(q.y); a[6] = bfs(q.z); a[7] = bfs(q.w);
#pragma unroll
      for (int ct = 0; ct < 4; ++ct)
        acc[ct] = __builtin_amdgcn_mfma_f32_16x16x32_bf16(a, bfr[kt][ct], acc[ct], 0, 0, 0);
    }
    int rbase = (lane >> 4) * 4;
#pragma unroll
    for (int reg = 0; reg < 4; ++reg) {
      int n = n0 + rbase + reg;
      float d = dinv[n];
#pragma unroll
      for (int ct = 0; ct < 4; ++ct)
        Y[(size_t)n * GH + ct * 16 + fcol] = (ushort)f2bf(acc[ct][reg] * d);
    }
  }
}

// ---- MFMA matmul, layers 2/3: X bf16 [NN,64] @ W[64,64] -> bf16 Y, *dinv ----
__global__ __launch_bounds__(TPB, 1)
void k_mmh(const ushort* __restrict__ X, const float* __restrict__ W,
           const float* __restrict__ dinv, ushort* __restrict__ Y) {
  int lane = threadIdx.x & 63;
  int wv = blockIdx.x * (TPB / 64) + (threadIdx.x >> 6);
  const int nwv = MMBLK * (TPB / 64);
  int kb = (lane >> 4) * 8;
  int fcol = lane & 15;
  bf16x8 bfr[2][4];
#pragma unroll
  for (int kt = 0; kt < 2; ++kt)
#pragma unroll
    for (int ct = 0; ct < 4; ++ct)
#pragma unroll
      for (int j = 0; j < 8; ++j)
        bfr[kt][ct][j] = bfs(W[(size_t)(kt * 32 + kb + j) * GH + ct * 16 + fcol]);
  const int NT = NN / 16;
  for (int t = wv; t < NT; t += nwv) {
    int n0 = t * 16;
    const ushort* xr = X + (size_t)(n0 + fcol) * GH;
    f32x4 acc[4] = {{0,0,0,0},{0,0,0,0},{0,0,0,0},{0,0,0,0}};
#pragma unroll
    for (int kt = 0; kt < 2; ++kt) {
      bf16x8 a = *(const bf16x8*)(xr + kt * 32 + kb);
#pragma unroll
      for (int ct = 0; ct < 4; ++ct)
        acc[ct] = __builtin_amdgcn_mfma_f32_16x16x32_bf16(a, bfr[kt][ct], acc[ct], 0, 0, 0);
    }
    int rbase = (lane >> 4) * 4;
#pragma unroll
    for (int reg = 0; reg < 4; ++reg) {
      int n = n0 + rbase + reg;
      float d = dinv[n];
#pragma unroll
      for (int ct = 0; ct < 4; ++ct)
        Y[(size_t)n * GH + ct * 16 + fcol] = (ushort)f2bf(acc[ct][reg] * d);
    }
  }
}

// Aggregation v3: 8 nodes per wave, 8 lanes per node (lane fq owns feats
// fq*8..fq*8+7 across the node's WHOLE edge list). Zero cross-lane reduce;
// all 64 lanes compute and write. Unroll-4 -> 4 gathers in flight per lane.
template<bool RELU, bool SCALE_SRC, bool BIAS>
__global__ void k_agg(const int* __restrict__ rowptr, const int* __restrict__ esrc,
                      const float* __restrict__ dinv, const uint4* __restrict__ hp,
                      const float* __restrict__ bias, uint4* __restrict__ out) {
  int wv = blockIdx.x * (TPB / 64) + (threadIdx.x >> 6);
  int lane = threadIdx.x & 63;
  int n = wv * 8 + (lane >> 3);
  if (n >= NN) return;
  int fq = lane & 7;
  int s0 = rowptr[n], s1 = rowptr[n + 1];
  float acc[8] = {0.f, 0.f, 0.f, 0.f, 0.f, 0.f, 0.f, 0.f};
#define ACC8(v, d)                                             \
  acc[0] += bflo((v).x) * (d); acc[1] += bfhi((v).x) * (d);    \
  acc[2] += bflo((v).y) * (d); acc[3] += bfhi((v).y) * (d);    \
  acc[4] += bflo((v).z) * (d); acc[5] += bfhi((v).z) * (d);    \
  acc[6] += bflo((v).w) * (d); acc[7] += bfhi((v).w) * (d);
  int e = s0;
  for (; e + 3 < s1; e += 4) {
    int r0 = esrc[e], r1 = esrc[e + 1], r2 = esrc[e + 2], r3 = esrc[e + 3];
    uint4 v0 = hp[(size_t)r0 * 8 + fq];
    uint4 v1 = hp[(size_t)r1 * 8 + fq];
    uint4 v2 = hp[(size_t)r2 * 8 + fq];
    uint4 v3 = hp[(size_t)r3 * 8 + fq];
    float d0 = 1.f, d1 = 1.f, d2 = 1.f, d3 = 1.f;
    if (SCALE_SRC) { d0 = dinv[r0]; d1 = dinv[r1]; d2 = dinv[r2]; d3 = dinv[r3]; }
    ACC8(v0, d0) ACC8(v1, d1) ACC8(v2, d2) ACC8(v3, d3)
  }
  for (; e < s1; ++e) {
    int r = esrc[e];
    uint4 v = hp[(size_t)r * 8 + fq];
    float d = SCALE_SRC ? dinv[r] : 1.f;
    ACC8(v, d)
  }
#undef ACC8
  float dn = dinv[n];
  uint4 sv = hp[(size_t)n * 8 + fq];
  float sc = SCALE_SRC ? dn : 1.f;
  float r8[8];
  r8[0] = (acc[0] + bflo(sv.x) * sc) * dn; r8[1] = (acc[1] + bfhi(sv.x) * sc) * dn;
  r8[2] = (acc[2] + bflo(sv.y) * sc) * dn; r8[3] = (acc[3] + bfhi(sv.y) * sc) * dn;
  r8[4] = (acc[4] + bflo(sv.z) * sc) * dn; r8[5] = (acc[5] + bfhi(sv.z) * sc) * dn;
  r8[6] = (acc[6] + bflo(sv.w) * sc) * dn; r8[7] = (acc[7] + bfhi(sv.w) * sc) * dn;
  if (BIAS) {
    const float4* b4p = (const float4*)bias;
    float4 bA = b4p[fq * 2], bB = b4p[fq * 2 + 1];
    r8[0] += bA.x; r8[1] += bA.y; r8[2] += bA.z; r8[3] += bA.w;
    r8[4] += bB.x; r8[5] += bB.y; r8[6] += bB.z; r8[7] += bB.w;
  }
  if (RELU) {
#pragma unroll
    for (int i = 0; i < 8; ++i) r8[i] = fmaxf(r8[i], 0.f);
  }
  uint4 o;
  o.x = pack2(r8[0], r8[1]); o.y = pack2(r8[2], r8[3]);
  o.z = pack2(r8[4], r8[5]); o.w = pack2(r8[6], r8[7]);
  out[(size_t)n * 8 + fq] = o;
}

// Merged pool + head: one block per graph. Binary-search bounds on sorted
// batch, segmented sum of agg4 rows, then W4/b4 + log_softmax (wave 0).
__global__ void k_poolhead(const ushort* __restrict__ agg4, const int* __restrict__ batch,
                           const float* __restrict__ W4, const float* __restrict__ b4,
                           float* __restrict__ out) {
  __shared__ float part[4][GH];
  __shared__ int se[2];
  int g = blockIdx.x;
  if (threadIdx.x < 2) {
    int key = g + threadIdx.x;
    int lo = 0, hi = NN;
    while (lo < hi) { int mid = (lo + hi) >> 1; if (batch[mid] < key) lo = mid + 1; else hi = mid; }
    se[threadIdx.x] = lo;
  }
  __syncthreads();
  int a = se[0], b = se[1];
  int f = threadIdx.x & 63, r = threadIdx.x >> 6;
  float acc = 0.f;
  for (int n = a + r; n < b; n += 4)
    acc += __uint_as_float(((uint32_t)agg4[(size_t)n * GH + f]) << 16);
  part[r][f] = acc;
  __syncthreads();
  if (r == 0) {
    float c = fmaxf((float)(b - a), 1.0f);
    float p = (part[0][f] + part[1][f] + part[2][f] + part[3][f]) / c;
    float t[GOUT];
#pragma unroll
    for (int j = 0; j < GOUT; ++j) {
      float rr = p * W4[f * GOUT + j];
#pragma unroll
      for (int off = 1; off < 64; off <<= 1) rr += __shfl_xor(rr, off);
      t[j] = rr + b4[j];
    }
    if (f == 0) {
      float mx = -1e30f;
#pragma unroll
      for (int j = 0; j < GOUT; ++j) mx = fmaxf(mx, t[j]);
      float sum = 0.f;
#pragma unroll
      for (int j = 0; j < GOUT; ++j) sum += expf(t[j] - mx);
      float lse = mx + logf(sum);
#pragma unroll
      for (int j = 0; j < GOUT; ++j) out[(size_t)g * GOUT + j] = t[j] - lse;
    }
  }
}

static inline int cdiv(long a, long b) { return (int)((a + b - 1) / b); }

extern "C" void kernel_launch(void* const* d_in, const int* in_sizes, int n_in,
                              void* d_out, int out_size, void* d_ws, size_t ws_size,
                              hipStream_t stream) {
  const float* x  = (const float*)d_in[0];
  const int*   ei = (const int*)d_in[1];
  const int*   bt = (const int*)d_in[2];
  const float* W1 = (const float*)d_in[3];
  const float* b1 = (const float*)d_in[4];
  const float* W2 = (const float*)d_in[5];
  const float* b2 = (const float*)d_in[6];
  const float* W3 = (const float*)d_in[7];
  const float* b3 = (const float*)d_in[8];
  const float* W4 = (const float*)d_in[9];
  const float* b4 = (const float*)d_in[10];
  float* out = (float*)d_out;

  ushort* HP      = (ushort*)d_ws;                    // NN*64 bf16
  ushort* ACT     = HP + (size_t)NN * GH;             // NN*64 bf16
  float* dinv     = (float*)(ACT + (size_t)NN * GH);  // NN
  int* rowptr     = (int*)(dinv + NN);                // NN+1
  int* esrc       = rowptr + NN + 3;                  // NE
  uint32_t* packed= (uint32_t*)(esrc + NE);           // NE
  int* cntm       = (int*)(packed + NE);              // BA*NBKT
  int* bas        = cntm + (size_t)BA * NBKT;         // BA*NBKT
  int* btot       = bas + (size_t)BA * NBKT;          // NBKT
  int* ebase      = btot + NBKT;                      // NBKT+1

  const int* row = ei;        // edge_index[0] = source
  const int* col = ei + NE;   // edge_index[1] = target (aggregate here)

  // --- bucketed CSR build (atomic-free) ---
  k_bcount<<<BA, TPB, 0, stream>>>(col, cntm);
  k_cscan<<<NBKT, TPB, 0, stream>>>(cntm, bas, btot);
  k_bscan<<<1, 64, 0, stream>>>(btot, ebase);
  k_bscatter<<<BA, TPB, 0, stream>>>(row, col, ebase, bas, packed);
  k_bbuild<<<NBKT, TPB, 0, stream>>>(packed, ebase, rowptr, dinv, esrc);

  const int gridA = cdiv(NN, (TPB / 64) * 8);  // 8 nodes per wave

  // --- layer 1 ---
  k_mm1<<<MMBLK, TPB, 0, stream>>>(x, W1, dinv, HP);
  k_agg<true, false, true><<<gridA, TPB, 0, stream>>>(rowptr, esrc, dinv, (const uint4*)HP, b1, (uint4*)ACT);
  // --- layer 2 ---
  k_mmh<<<MMBLK, TPB, 0, stream>>>(ACT, W2, dinv, HP);
  k_agg<true, false, true><<<gridA, TPB, 0, stream>>>(rowptr, esrc, dinv, (const uint4*)HP, b2, (uint4*)ACT);
  // --- layer 3 ---
  k_mmh<<<MMBLK, TPB, 0, stream>>>(ACT, W3, dinv, HP);
  k_agg<true, false, true><<<gridA, TPB, 0, stream>>>(rowptr, esrc, dinv, (const uint4*)HP, b3, (uint4*)ACT);
  // --- layer 4 (algebraic swap): AGG4 = Â·H3 into HP, no bias/relu ---
  k_agg<false, true, false><<<gridA, TPB, 0, stream>>>(rowptr, esrc, dinv, (const uint4*)ACT, nullptr, (uint4*)HP);

  // --- merged pool + head ---
  k_poolhead<<<NG, TPB, 0, stream>>>(HP, bt, W4, b4, out);
}